// Round 8
// baseline (2568.848 us; speedup 1.0000x reference)
//
#include <hip/hip_runtime.h>
#include <stdint.h>

#define T_STEPS 256
#define BATCH   32
#define DIN     4096
#define HD      512
#define NREL    51
#define TB      8192      // T*B
#define SIXH    3072
#define FIVEH   2560
#define SREL    (NREL * HD)
#define PIWG    786432    // per-WG PI2 block (elems) = TB*6*16
#define SPIN_MAX (1 << 18)

typedef short bf16x8 __attribute__((ext_vector_type(8)));
typedef float f32x4  __attribute__((ext_vector_type(4)));

typedef __attribute__((address_space(1))) const void gvoid_t;
typedef __attribute__((address_space(3))) void lvoid_t;

__device__ inline float bf2f(unsigned short u) {
    return __uint_as_float(((unsigned int)u) << 16);
}
__device__ inline unsigned short f2bf(float f) {
    unsigned int x = __float_as_uint(f);
    x += 0x7fffu + ((x >> 16) & 1u);   // RNE
    return (unsigned short)(x >> 16);
}
__device__ inline float sigm(float x) { return 1.f / (1.f + expf(-x)); }

__device__ inline void gll16(const void* g, void* l) {
    __builtin_amdgcn_global_load_lds((gvoid_t*)g, (lvoid_t*)l, 16, 0, 0);
}

// ---------- phase 0: fp32 -> bf16 converts / splits / counter zero ----------
__global__ void k_cvt(const float* __restrict__ s, unsigned short* __restrict__ d, int n4) {
    int i = blockIdx.x * blockDim.x + threadIdx.x;
    int st = gridDim.x * blockDim.x;
    for (; i < n4; i += st) {
        float4 v = ((const float4*)s)[i];
        ushort4 o;
        o.x = f2bf(v.x); o.y = f2bf(v.y); o.z = f2bf(v.z); o.w = f2bf(v.w);
        ((ushort4*)d)[i] = o;
    }
}

__global__ void k_split(const float* __restrict__ s, unsigned short* __restrict__ dh,
                        unsigned short* __restrict__ dl, int n4) {
    int i = blockIdx.x * blockDim.x + threadIdx.x;
    int st = gridDim.x * blockDim.x;
    for (; i < n4; i += st) {
        float4 v = ((const float4*)s)[i];
        ushort4 oh, ol;
        oh.x = f2bf(v.x); ol.x = f2bf(v.x - bf2f(oh.x));
        oh.y = f2bf(v.y); ol.y = f2bf(v.y - bf2f(oh.y));
        oh.z = f2bf(v.z); ol.z = f2bf(v.z - bf2f(oh.z));
        oh.w = f2bf(v.w); ol.w = f2bf(v.w - bf2f(oh.w));
        ((ushort4*)dh)[i] = oh;
        ((ushort4*)dl)[i] = ol;
    }
}

__global__ void k_zero(int* __restrict__ p) {
    int i = blockIdx.x * blockDim.x + threadIdx.x;
    if (i < 2048) p[i] = 0;
}

// ---------- phase 1: PI2 = x @ W_in^T + b_in, per-WG layout ----------
__global__ __launch_bounds__(256) void k_gemm_pi(const unsigned short* __restrict__ xb,
                                                 const unsigned short* __restrict__ wb,
                                                 const float* __restrict__ bin,
                                                 unsigned short* __restrict__ PI2) {
    __shared__ unsigned short sA[128 * 32];
    __shared__ unsigned short sB[128 * 32];
    const int tid = threadIdx.x;
    const int w = tid >> 6, l = tid & 63;
    const int wr = w >> 1, wc = w & 1;
    const long brow = (long)blockIdx.y * 128;
    const long bcol = (long)blockIdx.x * 128;

    f32x4 acc[4][4] = {};

    const int c0 = w * 128 + l;
    const int r0 = c0 >> 2, kc0 = (c0 & 3) * 8;
    const int c1 = c0 + 64;
    const int r1 = c1 >> 2, kc1 = (c1 & 3) * 8;
    unsigned short* lds0A = sA + (w * 128) * 8;
    unsigned short* lds1A = sA + (w * 128 + 64) * 8;
    unsigned short* lds0B = sB + (w * 128) * 8;
    unsigned short* lds1B = sB + (w * 128 + 64) * 8;

    const int frow = l & 15, kg = (l >> 4) * 8;

    for (int k0 = 0; k0 < DIN; k0 += 32) {
        __syncthreads();
        gll16(xb + (brow + r0) * DIN + k0 + kc0, lds0A);
        gll16(xb + (brow + r1) * DIN + k0 + kc1, lds1A);
        gll16(wb + (bcol + r0) * DIN + k0 + kc0, lds0B);
        gll16(wb + (bcol + r1) * DIN + k0 + kc1, lds1B);
        __syncthreads();
        bf16x8 aF[4], bF[4];
#pragma unroll
        for (int m = 0; m < 4; ++m)
            aF[m] = *(const bf16x8*)(sA + (wr * 64 + m * 16 + frow) * 32 + kg);
#pragma unroll
        for (int n = 0; n < 4; ++n)
            bF[n] = *(const bf16x8*)(sB + (wc * 64 + n * 16 + frow) * 32 + kg);
#pragma unroll
        for (int m = 0; m < 4; ++m)
#pragma unroll
            for (int n = 0; n < 4; ++n)
                acc[m][n] = __builtin_amdgcn_mfma_f32_16x16x32_bf16(aF[m], bF[n], acc[m][n], 0, 0, 0);
    }

#pragma unroll
    for (int m = 0; m < 4; ++m) {
#pragma unroll
        for (int n = 0; n < 4; ++n) {
            const long col = bcol + wc * 64 + n * 16 + (l & 15);
            const float bv = bin[col];
            const int g = (int)(col >> 9);
            const int cc = (int)(col & 511);
            const size_t base = (size_t)(cc >> 4) * PIWG + (size_t)(g * 16 + (cc & 15));
#pragma unroll
            for (int r = 0; r < 4; ++r) {
                const long row = brow + wr * 64 + m * 16 + (l >> 4) * 4 + r;
                PI2[base + (size_t)row * 96] = f2bf(acc[m][n][r] + bv);
            }
        }
    }
}

// ---------- phase 2: persistent recurrence, agent-scope (PROVEN) sync ----------
// 32 WGs x 256 thr, plain launch. WG j owns h-columns [16j,16j+16).
// Sync substrate = round-3-proven: __hip_atomic RELAXED/AGENT + __syncthreads
// drains. Barrier = per-step monotonic counter (one atomicAdd + one-line poll).
// W-hi in registers; W-lo in per-lane-linear LDS (conflict-free); h state =
// packed (hi<<16|lo) u32 planes with parity double-buffer; c state in LDS.
__global__ __launch_bounds__(256, 1) void k_recur(
    const int* __restrict__ rel, const float* __restrict__ h0,
    const float* __restrict__ c0, const unsigned short* __restrict__ PI2,
    const unsigned short* __restrict__ wsh, const unsigned short* __restrict__ wsl,
    const float* __restrict__ bst, const float* __restrict__ drop,
    unsigned int* __restrict__ Hp, int* __restrict__ ctr, float* __restrict__ Hs)
{
    __shared__ unsigned short piB[2][3072];        // 12 KB PI slabs (dbuf)
    __shared__ int relS[T_STEPS * BATCH];          // 32 KB
    __shared__ unsigned long long pref[T_STEPS];   // 2 KB parity masks
    __shared__ float cS[NREL * 16];                // 3.25 KB c state
    __shared__ float red[2][5][256];               // 10 KB
    __shared__ unsigned short Wlo[5120 * 8];       // 80 KB, per-lane-linear

    const int tid = threadIdx.x;
    const int w = tid >> 6, l = tid & 63;
    const int slot = blockIdx.x;
    const int hc0 = slot * 16;
    const unsigned short* slabBase = PI2 + (size_t)slot * PIWG;

    for (int i = tid; i < T_STEPS * BATCH; i += 256) relS[i] = rel[i];
    __syncthreads();

    // per-step parity-prefix masks
    {
        unsigned long long f = 0;
        for (int b = 0; b < BATCH; ++b) f ^= 1ull << relS[tid * BATCH + b];
        pref[tid] = f;
    }
    __syncthreads();
    if (tid == 0) {
        unsigned long long run = 0;
        for (int t = 0; t < T_STEPS; ++t) {
            const unsigned long long f = pref[t];
            pref[t] = run;
            run ^= f;
        }
    }

    // W-lo -> LDS, per-lane-linear layout [kh][g][kk][lane] x 16B (no conflicts)
    for (int i = tid; i < 5120; i += 256) {
        const int kh2 = i / 2560, r2 = i % 2560;
        const int g2 = r2 / 512, r3 = r2 % 512;
        const int kk2 = r3 / 64, l2 = r3 % 64;
        const int fr2 = l2 & 15, ko2 = l2 >> 4;
        const bf16x8 v = *(const bf16x8*)(wsl + (size_t)(g2 * HD + hc0 + fr2) * HD
                                          + kh2 * 256 + kk2 * 32 + ko2 * 8);
        *(bf16x8*)(Wlo + (size_t)i * 8) = v;
    }

    const int m = w & 1, kh = w >> 1;
    const int frow = l & 15, koff = l >> 4;
    const int col = hc0 + frow;

    // W-hi slice -> registers (160 VGPR/thread; budget 512 at 1 wave/SIMD)
    bf16x8 Wr[5][8];
#pragma unroll
    for (int g = 0; g < 5; ++g)
#pragma unroll
        for (int kk = 0; kk < 8; ++kk)
            Wr[g][kk] = *(const bf16x8*)(wsh + (size_t)(g * HD + hc0 + frow) * HD
                                         + kh * 256 + kk * 32 + koff * 8);

    // init c (LDS) and h parity-0 plane (agent-scope packed stores)
    for (int i = tid; i < NREL * 16; i += 256) {
        const int r = i >> 4, c = hc0 + (i & 15);
        cS[i] = c0[r * HD + c];
        const float hv = h0[r * HD + c];
        const unsigned short hi = f2bf(hv);
        const unsigned short lo = f2bf(hv - bf2f(hi));
        const unsigned int pk = ((unsigned int)hi << 16) | lo;
        __hip_atomic_store(&Hp[r * HD + c], pk, __ATOMIC_RELAXED, __HIP_MEMORY_SCOPE_AGENT);
    }

    // prefetch PI slab 0
    gll16(slabBase + (w * 64 + l) * 8, &piB[0][0] + w * 512);
    if (w < 2) gll16(slabBase + (256 + w * 64 + l) * 8, &piB[0][0] + 2048 + w * 512);

    float bs0 = 0, bs1 = 0, bs2 = 0, bs3 = 0, bs4 = 0;
    float dropv[4] = {};
    if (w < 2) {
        bs0 = bst[col]; bs1 = bst[HD + col]; bs2 = bst[2 * HD + col];
        bs3 = bst[3 * HD + col]; bs4 = bst[4 * HD + col];
#pragma unroll
        for (int r = 0; r < 4; ++r)
            dropv[r] = drop[(w * 16 + (l >> 4) * 4 + r) * HD + col];
    }

    // initial barrier: ctr[0] counts init completion
    __syncthreads();   // drains init stores per wave
    if (tid == 0) {
        atomicAdd(&ctr[0], 1);
        int v, it = 0;
        do { v = __hip_atomic_load(&ctr[0], __ATOMIC_RELAXED, __HIP_MEMORY_SCOPE_AGENT); }
        while (v < 32 && ++it < SPIN_MAX);
    }
    __syncthreads();

    for (int t = 0; t < T_STEPS; ++t) {
        const unsigned long long pm = pref[t];

        // prefetch next PI slab into the other LDS half
        if (t + 1 < T_STEPS) {
            const unsigned short* gsl = slabBase + (size_t)(t + 1) * 3072;
            unsigned short* dst = &piB[(t + 1) & 1][0];
            gll16(gsl + (w * 64 + l) * 8, dst + w * 512);
            if (w < 2) gll16(gsl + (256 + w * 64 + l) * 8, dst + 2048 + w * 512);
        }

        // gather h rows (agent-scope u64 loads, packed hi|lo)
        const int b = m * 16 + frow;
        const int id = relS[t * BATCH + b];
        const unsigned int* hrow = Hp + (int)((pm >> id) & 1) * SREL + id * HD + kh * 256 + koff * 8;
        unsigned long long rw[32];
#pragma unroll
        for (int kk = 0; kk < 8; ++kk) {
            const unsigned long long* p8 = (const unsigned long long*)(hrow + kk * 32);
#pragma unroll
            for (int j = 0; j < 4; ++j)
                rw[kk * 4 + j] = __hip_atomic_load(&p8[j], __ATOMIC_RELAXED, __HIP_MEMORY_SCOPE_AGENT);
        }

        // unpack to hi/lo bf16x8 fragments
        bf16x8 ah[8], al[8];
#pragma unroll
        for (int kk = 0; kk < 8; ++kk) {
            union { unsigned int u[4]; bf16x8 v; } ch, cl;
#pragma unroll
            for (int j = 0; j < 4; ++j) {
                const unsigned int w0 = (unsigned int)rw[kk * 4 + j];
                const unsigned int w1 = (unsigned int)(rw[kk * 4 + j] >> 32);
                ch.u[j] = (w0 >> 16) | (w1 & 0xFFFF0000u);
                cl.u[j] = (w0 & 0xFFFFu) | (w1 << 16);
            }
            ah[kk] = ch.v; al[kk] = cl.v;
        }

        // MFMA: 3 passes (h_hi*W_hi, h_lo*W_hi, h_hi*W_lo), independent chains
        f32x4 acch[5] = {}, accl[5] = {}, accw[5] = {};
#pragma unroll
        for (int kk = 0; kk < 8; ++kk)
#pragma unroll
            for (int g = 0; g < 5; ++g)
                acch[g] = __builtin_amdgcn_mfma_f32_16x16x32_bf16(ah[kk], Wr[g][kk], acch[g], 0, 0, 0);
#pragma unroll
        for (int kk = 0; kk < 8; ++kk)
#pragma unroll
            for (int g = 0; g < 5; ++g)
                accl[g] = __builtin_amdgcn_mfma_f32_16x16x32_bf16(al[kk], Wr[g][kk], accl[g], 0, 0, 0);
#pragma unroll
        for (int kk = 0; kk < 8; ++kk)
#pragma unroll
            for (int g = 0; g < 5; ++g) {
                const bf16x8 wl = *(const bf16x8*)(Wlo + (size_t)((((kh * 5 + g) * 8 + kk) * 64) + l) * 8);
                accw[g] = __builtin_amdgcn_mfma_f32_16x16x32_bf16(ah[kk], wl, accw[g], 0, 0, 0);
            }

        if (w >= 2) {
#pragma unroll
            for (int g = 0; g < 5; ++g) {
                const f32x4 s = acch[g] + accl[g] + accw[g];
                *(f32x4*)&red[w - 2][g][l * 4] = s;
            }
        }
        __syncthreads();   // red visible; PI slab DMA drained

        if (w < 2) {
            float ps[5][4];
#pragma unroll
            for (int g = 0; g < 5; ++g) {
                const f32x4 s1 = *(const f32x4*)&red[w][g][l * 4];
#pragma unroll
                for (int r = 0; r < 4; ++r)
                    ps[g][r] = acch[g][r] + accl[g][r] + accw[g][r] + s1[r];
            }
            const unsigned short* pb = &piB[t & 1][0];
#pragma unroll
            for (int r = 0; r < 4; ++r) {
                const int b2 = w * 16 + (l >> 4) * 4 + r;
                const int grow = t * BATCH + b2;
                const int id2 = relS[grow];
                const unsigned short* pr = pb + b2 * 96 + frow;
                const float pii = bf2f(pr[0]);
                const float pif = bf2f(pr[16]);
                const float pig = bf2f(pr[32]);
                const float pio = bf2f(pr[48]);
                const float piw = bf2f(pr[64]);
                const float pip = bf2f(pr[80]);
                const float ig = sigm(pii + ps[0][r] + bs0);
                const float fg = sigm(pif + ps[1][r] + bs1);
                const float gg = tanhf(pig + ps[2][r] + bs2);
                const float og = sigm(pio + ps[3][r] + bs3);
                const float hw = sigm(piw + ps[4][r] + bs4);
                const float cp = cS[id2 * 16 + frow];
                const float cn = ig * gg + fg * cp;
                float h = og * tanhf(cn);
                h = hw * h + (1.f - hw) * pip;
                h *= dropv[r];
                cS[id2 * 16 + frow] = cn;
                const unsigned short hhi = f2bf(h);
                const unsigned short hlo = f2bf(h - bf2f(hhi));
                const unsigned int pk = ((unsigned int)hhi << 16) | hlo;
                const int pw = (int)(((pm >> id2) & 1) ^ 1ull);
                __hip_atomic_store(&Hp[pw * SREL + id2 * HD + col], pk,
                                   __ATOMIC_RELAXED, __HIP_MEMORY_SCOPE_AGENT);
                Hs[(size_t)grow * HD + col] = h;
            }
        }

        // barrier: counter t+1 (arrive after full drain, single-line poll)
        __syncthreads();   // drains the h publishes of waves 0-1
        if (tid == 0) {
            atomicAdd(&ctr[t + 1], 1);
            int v, it = 0;
            do { v = __hip_atomic_load(&ctr[t + 1], __ATOMIC_RELAXED, __HIP_MEMORY_SCOPE_AGENT); }
            while (v < 32 && ++it < SPIN_MAX);
        }
        __syncthreads();
    }
}

// ---------- phase 3: preds = Hs @ W_out^T + b_out (fp32) ----------
__global__ __launch_bounds__(256) void k_pred(const float* __restrict__ Hs,
                                              const float* __restrict__ Wout,
                                              const float* __restrict__ bout,
                                              float* __restrict__ out) {
    __shared__ float hT[16 * HD];
    const int tid = threadIdx.x;
    const long row0 = (long)blockIdx.x * 16;
    for (int i = tid; i < (16 * HD) / 4; i += 256)
        ((float4*)hT)[i] = ((const float4*)(Hs + row0 * HD))[i];
    __syncthreads();
    const int w = tid >> 6, c = tid & 63;
    if (c < NREL) {
        float a0 = bout[c], a1 = a0, a2 = a0, a3 = a0;
        const float* wrp = Wout + c * HD;
        for (int k = 0; k < HD; k += 4) {
            const float4 wv = *(const float4*)(wrp + k);
            const float4 h0 = *(const float4*)(hT + (w * 4 + 0) * HD + k);
            const float4 h1 = *(const float4*)(hT + (w * 4 + 1) * HD + k);
            const float4 h2 = *(const float4*)(hT + (w * 4 + 2) * HD + k);
            const float4 h3 = *(const float4*)(hT + (w * 4 + 3) * HD + k);
            a0 += wv.x * h0.x + wv.y * h0.y + wv.z * h0.z + wv.w * h0.w;
            a1 += wv.x * h1.x + wv.y * h1.y + wv.z * h1.z + wv.w * h1.w;
            a2 += wv.x * h2.x + wv.y * h2.y + wv.z * h2.z + wv.w * h2.w;
            a3 += wv.x * h3.x + wv.y * h3.y + wv.z * h3.z + wv.w * h3.w;
        }
        out[(row0 + w * 4 + 0) * NREL + c] = a0;
        out[(row0 + w * 4 + 1) * NREL + c] = a1;
        out[(row0 + w * 4 + 2) * NREL + c] = a2;
        out[(row0 + w * 4 + 3) * NREL + c] = a3;
    }
}

extern "C" void kernel_launch(void* const* d_in, const int* in_sizes, int n_in,
                              void* d_out, int out_size, void* d_ws, size_t ws_size,
                              hipStream_t stream) {
    const float* x    = (const float*)d_in[0];
    const int*   rel  = (const int*)  d_in[1];
    const float* h0   = (const float*)d_in[2];
    const float* c0   = (const float*)d_in[3];
    const float* Win  = (const float*)d_in[4];
    const float* bin  = (const float*)d_in[5];
    const float* Wst  = (const float*)d_in[6];
    const float* bst  = (const float*)d_in[7];
    const float* Wout = (const float*)d_in[8];
    const float* bout = (const float*)d_in[9];
    const float* drop = (const float*)d_in[10];

    char* ws = (char*)d_ws;
    // workspace layout (bytes), total 164,843,520
    unsigned short* xb  = (unsigned short*)(ws);              // 67,108,864
    unsigned short* wb  = (unsigned short*)(ws + 67108864);   // 25,165,824
    unsigned short* wsh = (unsigned short*)(ws + 92274688);   //  2,621,440
    unsigned short* wsl = (unsigned short*)(ws + 94896128);   //  2,621,440
    unsigned short* PI2 = (unsigned short*)(ws + 97517568);   // 50,331,648
    unsigned int*   Hp  = (unsigned int*)  (ws + 147849216);  //    208,896 (2 parities)
    float*          Hs  = (float*)         (ws + 148058112);  // 16,777,216
    int*            ctr = (int*)           (ws + 164835328);  //      8,192
    float* out = (float*)d_out;

    k_zero<<<8, 256, 0, stream>>>(ctr);
    k_cvt<<<2048, 256, 0, stream>>>(x, xb, (TB * DIN) / 4);
    k_cvt<<<1024, 256, 0, stream>>>(Win, wb, (SIXH * DIN) / 4);
    k_split<<<320, 256, 0, stream>>>(Wst, wsh, wsl, (FIVEH * HD) / 4);

    k_gemm_pi<<<dim3(SIXH / 128, TB / 128), 256, 0, stream>>>(xb, wb, bin, PI2);

    k_recur<<<32, 256, 0, stream>>>(rel, h0, c0, PI2, wsh, wsl, bst, drop, Hp, ctr, Hs);

    k_pred<<<512, 256, 0, stream>>>(Hs, Wout, bout, out);
}

// Round 9
// 2128.412 us; speedup vs baseline: 1.2069x; 1.2069x over previous
//
#include <hip/hip_runtime.h>
#include <stdint.h>

#define T_STEPS 256
#define BATCH   32
#define DIN     4096
#define HD      512
#define NREL    51
#define TB      8192      // T*B
#define SIXH    3072
#define FIVEH   2560
#define SREL    (NREL * HD)
#define PIWG    786432    // per-WG PI2 block (elems) = TB*6*16
#define SPIN_MAX (1 << 18)

typedef short bf16x8 __attribute__((ext_vector_type(8)));
typedef float f32x4  __attribute__((ext_vector_type(4)));
typedef unsigned int u32x4 __attribute__((ext_vector_type(4)));

union V16 { u32x4 u; bf16x8 v; };

typedef __attribute__((address_space(1))) const void gvoid_t;
typedef __attribute__((address_space(3))) void lvoid_t;

__device__ inline float bf2f(unsigned short u) {
    return __uint_as_float(((unsigned int)u) << 16);
}
__device__ inline unsigned short f2bf(float f) {
    unsigned int x = __float_as_uint(f);
    x += 0x7fffu + ((x >> 16) & 1u);   // RNE
    return (unsigned short)(x >> 16);
}
__device__ inline float sigm(float x) { return 1.f / (1.f + expf(-x)); }

__device__ inline void gll16(const void* g, void* l) {
    __builtin_amdgcn_global_load_lds((gvoid_t*)g, (lvoid_t*)l, 16, 0, 0);
}

// 16 L3-coherent (bypass L1+L2: sc0 sc1) 16B loads from the hi/lo h planes.
#define GATHER_PLANES(H, L, HP, LP, TAIL) \
  asm volatile( \
    "global_load_dwordx4 %0, %16, off sc0 sc1\n\t" \
    "global_load_dwordx4 %1, %16, off offset:64 sc0 sc1\n\t" \
    "global_load_dwordx4 %2, %16, off offset:128 sc0 sc1\n\t" \
    "global_load_dwordx4 %3, %16, off offset:192 sc0 sc1\n\t" \
    "global_load_dwordx4 %4, %16, off offset:256 sc0 sc1\n\t" \
    "global_load_dwordx4 %5, %16, off offset:320 sc0 sc1\n\t" \
    "global_load_dwordx4 %6, %16, off offset:384 sc0 sc1\n\t" \
    "global_load_dwordx4 %7, %16, off offset:448 sc0 sc1\n\t" \
    "global_load_dwordx4 %8, %17, off sc0 sc1\n\t" \
    "global_load_dwordx4 %9, %17, off offset:64 sc0 sc1\n\t" \
    "global_load_dwordx4 %10, %17, off offset:128 sc0 sc1\n\t" \
    "global_load_dwordx4 %11, %17, off offset:192 sc0 sc1\n\t" \
    "global_load_dwordx4 %12, %17, off offset:256 sc0 sc1\n\t" \
    "global_load_dwordx4 %13, %17, off offset:320 sc0 sc1\n\t" \
    "global_load_dwordx4 %14, %17, off offset:384 sc0 sc1\n\t" \
    "global_load_dwordx4 %15, %17, off offset:448 sc0 sc1" TAIL \
    : "=v"(H[0].u), "=v"(H[1].u), "=v"(H[2].u), "=v"(H[3].u), \
      "=v"(H[4].u), "=v"(H[5].u), "=v"(H[6].u), "=v"(H[7].u), \
      "=v"(L[0].u), "=v"(L[1].u), "=v"(L[2].u), "=v"(L[3].u), \
      "=v"(L[4].u), "=v"(L[5].u), "=v"(L[6].u), "=v"(L[7].u) \
    : "v"(HP), "v"(LP) : "memory")

__device__ inline void coh_store_u16(unsigned short* p, unsigned int v) {
    asm volatile("global_store_short %0, %1, off sc0 sc1" :: "v"(p), "v"(v) : "memory");
}

// ---------- phase 0: fp32 -> bf16 converts / splits / counter zero ----------
__global__ void k_cvt(const float* __restrict__ s, unsigned short* __restrict__ d, int n4) {
    int i = blockIdx.x * blockDim.x + threadIdx.x;
    int st = gridDim.x * blockDim.x;
    for (; i < n4; i += st) {
        float4 v = ((const float4*)s)[i];
        ushort4 o;
        o.x = f2bf(v.x); o.y = f2bf(v.y); o.z = f2bf(v.z); o.w = f2bf(v.w);
        ((ushort4*)d)[i] = o;
    }
}

__global__ void k_split(const float* __restrict__ s, unsigned short* __restrict__ dh,
                        unsigned short* __restrict__ dl, int n4) {
    int i = blockIdx.x * blockDim.x + threadIdx.x;
    int st = gridDim.x * blockDim.x;
    for (; i < n4; i += st) {
        float4 v = ((const float4*)s)[i];
        ushort4 oh, ol;
        oh.x = f2bf(v.x); ol.x = f2bf(v.x - bf2f(oh.x));
        oh.y = f2bf(v.y); ol.y = f2bf(v.y - bf2f(oh.y));
        oh.z = f2bf(v.z); ol.z = f2bf(v.z - bf2f(oh.z));
        oh.w = f2bf(v.w); ol.w = f2bf(v.w - bf2f(oh.w));
        ((ushort4*)dh)[i] = oh;
        ((ushort4*)dl)[i] = ol;
    }
}

__global__ void k_zero(int* __restrict__ p) {
    int i = blockIdx.x * blockDim.x + threadIdx.x;
    if (i < 2048) p[i] = 0;
}

// ---------- phase 1: PI2 = x @ W_in^T + b_in, per-WG layout ----------
__global__ __launch_bounds__(256) void k_gemm_pi(const unsigned short* __restrict__ xb,
                                                 const unsigned short* __restrict__ wb,
                                                 const float* __restrict__ bin,
                                                 unsigned short* __restrict__ PI2) {
    __shared__ unsigned short sA[128 * 32];
    __shared__ unsigned short sB[128 * 32];
    const int tid = threadIdx.x;
    const int w = tid >> 6, l = tid & 63;
    const int wr = w >> 1, wc = w & 1;
    const long brow = (long)blockIdx.y * 128;
    const long bcol = (long)blockIdx.x * 128;

    f32x4 acc[4][4] = {};

    const int c0 = w * 128 + l;
    const int r0 = c0 >> 2, kc0 = (c0 & 3) * 8;
    const int c1 = c0 + 64;
    const int r1 = c1 >> 2, kc1 = (c1 & 3) * 8;
    unsigned short* lds0A = sA + (w * 128) * 8;
    unsigned short* lds1A = sA + (w * 128 + 64) * 8;
    unsigned short* lds0B = sB + (w * 128) * 8;
    unsigned short* lds1B = sB + (w * 128 + 64) * 8;

    const int frow = l & 15, kg = (l >> 4) * 8;

    for (int k0 = 0; k0 < DIN; k0 += 32) {
        __syncthreads();
        gll16(xb + (brow + r0) * DIN + k0 + kc0, lds0A);
        gll16(xb + (brow + r1) * DIN + k0 + kc1, lds1A);
        gll16(wb + (bcol + r0) * DIN + k0 + kc0, lds0B);
        gll16(wb + (bcol + r1) * DIN + k0 + kc1, lds1B);
        __syncthreads();
        bf16x8 aF[4], bF[4];
#pragma unroll
        for (int m = 0; m < 4; ++m)
            aF[m] = *(const bf16x8*)(sA + (wr * 64 + m * 16 + frow) * 32 + kg);
#pragma unroll
        for (int n = 0; n < 4; ++n)
            bF[n] = *(const bf16x8*)(sB + (wc * 64 + n * 16 + frow) * 32 + kg);
#pragma unroll
        for (int m = 0; m < 4; ++m)
#pragma unroll
            for (int n = 0; n < 4; ++n)
                acc[m][n] = __builtin_amdgcn_mfma_f32_16x16x32_bf16(aF[m], bF[n], acc[m][n], 0, 0, 0);
    }

#pragma unroll
    for (int m = 0; m < 4; ++m) {
#pragma unroll
        for (int n = 0; n < 4; ++n) {
            const long col = bcol + wc * 64 + n * 16 + (l & 15);
            const float bv = bin[col];
            const int g = (int)(col >> 9);
            const int cc = (int)(col & 511);
            const size_t base = (size_t)(cc >> 4) * PIWG + (size_t)(g * 16 + (cc & 15));
#pragma unroll
            for (int r = 0; r < 4; ++r) {
                const long row = brow + wr * 64 + m * 16 + (l >> 4) * 4 + r;
                PI2[base + (size_t)row * 96] = f2bf(acc[m][n][r] + bv);
            }
        }
    }
}

// ---------- phase 2: persistent recurrence, lean L3-coherent chain ----------
// 32 WGs x 256 thr. WG j owns h-columns [16j,16j+16). h = hi/lo ushort planes
// (parity double-buffered), published/gathered with raw sc0+sc1 (L3 coherence
// point). Barrier = per-wave atomicAdd arrival (proven) + single-line asm poll.
// Gates split over all 4 waves; Hs stores + PI prefetch issued off-chain.
__global__ __launch_bounds__(256, 1) void k_recur(
    const int* __restrict__ rel, const float* __restrict__ h0,
    const float* __restrict__ c0, const unsigned short* __restrict__ PI2,
    const unsigned short* __restrict__ wsh, const unsigned short* __restrict__ wsl,
    const float* __restrict__ bst, const float* __restrict__ drop,
    unsigned short* __restrict__ Hp, int* __restrict__ ctr, float* __restrict__ Hs)
{
    __shared__ unsigned short piB[2][3072];        // 12 KB PI slabs (dbuf)
    __shared__ unsigned char relS[T_STEPS * BATCH];// 8 KB
    __shared__ unsigned long long pref[T_STEPS];   // 2 KB parity masks
    __shared__ float cS[NREL * 16];                // 3.25 KB c state
    __shared__ float red[2][2][5][256];            // 40 KB partial exchange
    __shared__ unsigned short Wlo[5120 * 8];       // 80 KB, per-lane-linear

    const int tid = threadIdx.x;
    const int w = tid >> 6, l = tid & 63;
    const int slot = blockIdx.x;
    const int hc0 = slot * 16;
    const unsigned short* slabBase = PI2 + (size_t)slot * PIWG;
    unsigned short* HpL = Hp + 2 * SREL;           // lo planes base

    for (int i = tid; i < T_STEPS * BATCH; i += 256) relS[i] = (unsigned char)rel[i];
    __syncthreads();

    // per-step parity-prefix masks
    {
        unsigned long long f = 0;
        for (int b = 0; b < BATCH; ++b) f ^= 1ull << relS[tid * BATCH + b];
        pref[tid] = f;
    }
    __syncthreads();
    if (tid == 0) {
        unsigned long long run = 0;
        for (int t = 0; t < T_STEPS; ++t) {
            const unsigned long long f = pref[t];
            pref[t] = run;
            run ^= f;
        }
    }

    // W-lo -> LDS, per-lane-linear layout [kh][g][kk][lane] x 16B (no conflicts)
    for (int i = tid; i < 5120; i += 256) {
        const int kh2 = i / 2560, r2 = i % 2560;
        const int g2 = r2 / 512, r3 = r2 % 512;
        const int kk2 = r3 / 64, l2 = r3 % 64;
        const int fr2 = l2 & 15, ko2 = l2 >> 4;
        const bf16x8 v = *(const bf16x8*)(wsl + (size_t)(g2 * HD + hc0 + fr2) * HD
                                          + kh2 * 256 + kk2 * 32 + ko2 * 8);
        *(bf16x8*)(Wlo + (size_t)i * 8) = v;
    }

    const int m = w & 1, kh = w >> 1;
    const int frow = l & 15, koff = l >> 4;
    const int col = hc0 + frow;

    // W-hi slice -> registers (160 VGPR/thread)
    bf16x8 Wr[5][8];
#pragma unroll
    for (int g = 0; g < 5; ++g)
#pragma unroll
        for (int kk = 0; kk < 8; ++kk)
            Wr[g][kk] = *(const bf16x8*)(wsh + (size_t)(g * HD + hc0 + frow) * HD
                                         + kh * 256 + kk * 32 + koff * 8);

    // init c (LDS) and h parity-0 planes (coherent u16 stores)
    for (int i = tid; i < NREL * 16; i += 256) {
        const int r = i >> 4, c = hc0 + (i & 15);
        cS[i] = c0[r * HD + c];
        const float hv = h0[r * HD + c];
        const unsigned short hi = f2bf(hv);
        coh_store_u16(Hp + r * HD + c, hi);
        coh_store_u16(HpL + r * HD + c, (unsigned int)f2bf(hv - bf2f(hi)));
    }

    // preload PI slab 0
    gll16(slabBase + (w * 64 + l) * 8, &piB[0][0] + w * 512);
    if (w < 2) gll16(slabBase + (256 + w * 64 + l) * 8, &piB[0][0] + 2048 + w * 512);

    float bs0 = bst[col], bs1 = bst[HD + col], bs2 = bst[2 * HD + col];
    float bs3 = bst[3 * HD + col], bs4 = bst[4 * HD + col];
    const int rA = kh * 2, rB = rA + 1;            // this wave's gate rows
    const int bA = m * 16 + (l >> 4) * 4 + rA;
    const int bB = bA + 1;
    const float dropA = drop[bA * HD + col];
    const float dropB = drop[bB * HD + col];

    // initial barrier: per-wave drain + arrival (target 128), tid0 polls
    __syncthreads();   // pref/Wlo/cS visible
    asm volatile("s_waitcnt vmcnt(0)" ::: "memory");
    if (l == 0) __hip_atomic_fetch_add(&ctr[0], 1, __ATOMIC_RELAXED, __HIP_MEMORY_SCOPE_AGENT);
    if (tid == 0) {
        const int* fp = &ctr[0];
        int fv, it = 0;
        do {
            asm volatile("global_load_dword %0, %1, off sc0 sc1\n\ts_waitcnt vmcnt(0)"
                         : "=v"(fv) : "v"(fp) : "memory");
        } while (fv < 128 && ++it < SPIN_MAX);
    }
    __syncthreads();

    for (int t = 0; t < T_STEPS; ++t) {
        const unsigned long long pm = pref[t];

        // ---- gather this step's h fragments (L3-coherent plane loads) ----
        const int id = relS[t * BATCH + m * 16 + frow];
        const unsigned short* hp = Hp + (int)((pm >> id) & 1) * SREL + id * HD + kh * 256 + koff * 8;
        const unsigned short* lp = hp + 2 * SREL;
        V16 hF[8], lF[8];
        GATHER_PLANES(hF, lF, hp, lp, "\n\ts_waitcnt vmcnt(0)");
        __builtin_amdgcn_sched_barrier(0);

        // ---- MFMA: 3 passes (h_hi*W_hi, h_lo*W_hi, h_hi*W_lo) ----
        f32x4 acch[5] = {}, accl[5] = {}, accw[5] = {};
#pragma unroll
        for (int kk = 0; kk < 8; ++kk)
#pragma unroll
            for (int g = 0; g < 5; ++g)
                acch[g] = __builtin_amdgcn_mfma_f32_16x16x32_bf16(hF[kk].v, Wr[g][kk], acch[g], 0, 0, 0);
#pragma unroll
        for (int kk = 0; kk < 8; ++kk)
#pragma unroll
            for (int g = 0; g < 5; ++g)
                accl[g] = __builtin_amdgcn_mfma_f32_16x16x32_bf16(lF[kk].v, Wr[g][kk], accl[g], 0, 0, 0);
#pragma unroll
        for (int kk = 0; kk < 8; ++kk)
#pragma unroll
            for (int g = 0; g < 5; ++g) {
                const bf16x8 wl = *(const bf16x8*)(Wlo + (size_t)((((kh * 5 + g) * 8 + kk) * 64) + l) * 8);
                accw[g] = __builtin_amdgcn_mfma_f32_16x16x32_bf16(hF[kk].v, wl, accw[g], 0, 0, 0);
            }

        // ---- symmetric partial exchange ----
#pragma unroll
        for (int g = 0; g < 5; ++g) {
            const f32x4 s = acch[g] + accl[g] + accw[g];
            *(f32x4*)&red[m][kh][g][l * 4] = s;
        }
        __syncthreads();   // red visible; also drains prev Hs stores + PI DMA

        // ---- gates for this wave's 2 rows ----
        float hOutA, hOutB;
        {
            float psA[5], psB[5];
#pragma unroll
            for (int g = 0; g < 5; ++g) {
                const f32x4 own = acch[g] + accl[g] + accw[g];
                const f32x4 oth = *(const f32x4*)&red[m][kh ^ 1][g][l * 4];
                psA[g] = own[rA] + oth[rA];
                psB[g] = own[rB] + oth[rB];
            }
            const unsigned short* pb = &piB[t & 1][0];
            const unsigned short* prA = pb + bA * 96 + frow;
            const unsigned short* prB = pb + bB * 96 + frow;
            const int idA = relS[t * BATCH + bA];
            const int idB = relS[t * BATCH + bB];
            // row A
            {
                const float ig = sigm(bf2f(prA[0])  + psA[0] + bs0);
                const float fg = sigm(bf2f(prA[16]) + psA[1] + bs1);
                const float gg = tanhf(bf2f(prA[32]) + psA[2] + bs2);
                const float og = sigm(bf2f(prA[48]) + psA[3] + bs3);
                const float hw = sigm(bf2f(prA[64]) + psA[4] + bs4);
                const float cp = cS[idA * 16 + frow];
                const float cn = ig * gg + fg * cp;
                float h = og * tanhf(cn);
                h = hw * h + (1.f - hw) * bf2f(prA[80]);
                h *= dropA;
                cS[idA * 16 + frow] = cn;
                const unsigned short hhi = f2bf(h);
                const int pw = (int)(((pm >> idA) & 1) ^ 1ull);
                coh_store_u16(Hp + pw * SREL + idA * HD + col, hhi);
                coh_store_u16(HpL + pw * SREL + idA * HD + col, (unsigned int)f2bf(h - bf2f(hhi)));
                hOutA = h;
            }
            // row B
            {
                const float ig = sigm(bf2f(prB[0])  + psB[0] + bs0);
                const float fg = sigm(bf2f(prB[16]) + psB[1] + bs1);
                const float gg = tanhf(bf2f(prB[32]) + psB[2] + bs2);
                const float og = sigm(bf2f(prB[48]) + psB[3] + bs3);
                const float hw = sigm(bf2f(prB[64]) + psB[4] + bs4);
                const float cp = cS[idB * 16 + frow];
                const float cn = ig * gg + fg * cp;
                float h = og * tanhf(cn);
                h = hw * h + (1.f - hw) * bf2f(prB[80]);
                h *= dropB;
                cS[idB * 16 + frow] = cn;
                const unsigned short hhi = f2bf(h);
                const int pw = (int)(((pm >> idB) & 1) ^ 1ull);
                coh_store_u16(Hp + pw * SREL + idB * HD + col, hhi);
                coh_store_u16(HpL + pw * SREL + idB * HD + col, (unsigned int)f2bf(h - bf2f(hhi)));
                hOutB = h;
            }
        }

        // ---- per-wave drain + arrival (chain waits only on 4 h-publishes) ----
        asm volatile("s_waitcnt vmcnt(0)" ::: "memory");
        if (l == 0) __hip_atomic_fetch_add(&ctr[t + 1], 1, __ATOMIC_RELAXED, __HIP_MEMORY_SCOPE_AGENT);

        // ---- off-chain: Hs log + next PI slab prefetch ----
        Hs[(size_t)(t * BATCH + bA) * HD + col] = hOutA;
        Hs[(size_t)(t * BATCH + bB) * HD + col] = hOutB;
        if (t + 1 < T_STEPS) {
            const unsigned short* gsl = slabBase + (size_t)(t + 1) * 3072;
            unsigned short* dst = &piB[(t + 1) & 1][0];
            gll16(gsl + (w * 64 + l) * 8, dst + w * 512);
            if (w < 2) gll16(gsl + (256 + w * 64 + l) * 8, dst + 2048 + w * 512);
        }

        // ---- wait for all 128 waves, release ----
        if (tid == 0) {
            const int* fp = &ctr[t + 1];
            int fv, it = 0;
            do {
                asm volatile("global_load_dword %0, %1, off sc0 sc1\n\ts_waitcnt vmcnt(0)"
                             : "=v"(fv) : "v"(fp) : "memory");
            } while (fv < 128 && ++it < SPIN_MAX);
        }
        __syncthreads();
    }
}

// ---------- phase 3: preds = Hs @ W_out^T + b_out (fp32) ----------
__global__ __launch_bounds__(256) void k_pred(const float* __restrict__ Hs,
                                              const float* __restrict__ Wout,
                                              const float* __restrict__ bout,
                                              float* __restrict__ out) {
    __shared__ float hT[16 * HD];
    const int tid = threadIdx.x;
    const long row0 = (long)blockIdx.x * 16;
    for (int i = tid; i < (16 * HD) / 4; i += 256)
        ((float4*)hT)[i] = ((const float4*)(Hs + row0 * HD))[i];
    __syncthreads();
    const int w = tid >> 6, c = tid & 63;
    if (c < NREL) {
        float a0 = bout[c], a1 = a0, a2 = a0, a3 = a0;
        const float* wrp = Wout + c * HD;
        for (int k = 0; k < HD; k += 4) {
            const float4 wv = *(const float4*)(wrp + k);
            const float4 h0 = *(const float4*)(hT + (w * 4 + 0) * HD + k);
            const float4 h1 = *(const float4*)(hT + (w * 4 + 1) * HD + k);
            const float4 h2 = *(const float4*)(hT + (w * 4 + 2) * HD + k);
            const float4 h3 = *(const float4*)(hT + (w * 4 + 3) * HD + k);
            a0 += wv.x * h0.x + wv.y * h0.y + wv.z * h0.z + wv.w * h0.w;
            a1 += wv.x * h1.x + wv.y * h1.y + wv.z * h1.z + wv.w * h1.w;
            a2 += wv.x * h2.x + wv.y * h2.y + wv.z * h2.z + wv.w * h2.w;
            a3 += wv.x * h3.x + wv.y * h3.y + wv.z * h3.z + wv.w * h3.w;
        }
        out[(row0 + w * 4 + 0) * NREL + c] = a0;
        out[(row0 + w * 4 + 1) * NREL + c] = a1;
        out[(row0 + w * 4 + 2) * NREL + c] = a2;
        out[(row0 + w * 4 + 3) * NREL + c] = a3;
    }
}

extern "C" void kernel_launch(void* const* d_in, const int* in_sizes, int n_in,
                              void* d_out, int out_size, void* d_ws, size_t ws_size,
                              hipStream_t stream) {
    const float* x    = (const float*)d_in[0];
    const int*   rel  = (const int*)  d_in[1];
    const float* h0   = (const float*)d_in[2];
    const float* c0   = (const float*)d_in[3];
    const float* Win  = (const float*)d_in[4];
    const float* bin  = (const float*)d_in[5];
    const float* Wst  = (const float*)d_in[6];
    const float* bst  = (const float*)d_in[7];
    const float* Wout = (const float*)d_in[8];
    const float* bout = (const float*)d_in[9];
    const float* drop = (const float*)d_in[10];

    char* ws = (char*)d_ws;
    // workspace layout (bytes), total ~164.9 MB
    unsigned short* xb  = (unsigned short*)(ws);              // 67,108,864
    unsigned short* wb  = (unsigned short*)(ws + 67108864);   // 25,165,824
    unsigned short* wsh = (unsigned short*)(ws + 92274688);   //  2,621,440
    unsigned short* wsl = (unsigned short*)(ws + 94896128);   //  2,621,440
    unsigned short* PI2 = (unsigned short*)(ws + 97517568);   // 50,331,648
    unsigned short* Hp  = (unsigned short*)(ws + 147849216);  //    208,896 (hi/lo x 2 parity)
    float*          Hs  = (float*)         (ws + 148058112);  // 16,777,216
    int*            ctr = (int*)           (ws + 164835328);  //      8,192
    float* out = (float*)d_out;

    k_zero<<<8, 256, 0, stream>>>(ctr);
    k_cvt<<<2048, 256, 0, stream>>>(x, xb, (TB * DIN) / 4);
    k_cvt<<<1024, 256, 0, stream>>>(Win, wb, (SIXH * DIN) / 4);
    k_split<<<320, 256, 0, stream>>>(Wst, wsh, wsl, (FIVEH * HD) / 4);

    k_gemm_pi<<<dim3(SIXH / 128, TB / 128), 256, 0, stream>>>(xb, wb, bin, PI2);

    k_recur<<<32, 256, 0, stream>>>(rel, h0, c0, PI2, wsh, wsl, bst, drop, Hp, ctr, Hs);

    k_pred<<<512, 256, 0, stream>>>(Hs, Wout, bout, out);
}

// Round 10
// 1955.020 us; speedup vs baseline: 1.3140x; 1.0887x over previous
//
#include <hip/hip_runtime.h>
#include <stdint.h>

#define T_STEPS 256
#define BATCH   32
#define DIN     4096
#define HD      512
#define NREL    51
#define TB      8192      // T*B
#define SIXH    3072
#define FIVEH   2560
#define SREL    (NREL * HD)
#define PIWG    786432    // per-WG PI2 block (elems) = TB*6*16
#define SPIN_MAX (1 << 18)

typedef short bf16x8 __attribute__((ext_vector_type(8)));
typedef float f32x4  __attribute__((ext_vector_type(4)));
typedef unsigned int u32x4 __attribute__((ext_vector_type(4)));

union V16 { u32x4 u; bf16x8 v; };

typedef __attribute__((address_space(1))) const void gvoid_t;
typedef __attribute__((address_space(3))) void lvoid_t;

__device__ inline float bf2f(unsigned short u) {
    return __uint_as_float(((unsigned int)u) << 16);
}
__device__ inline unsigned short f2bf(float f) {
    unsigned int x = __float_as_uint(f);
    x += 0x7fffu + ((x >> 16) & 1u);   // RNE
    return (unsigned short)(x >> 16);
}
__device__ inline float sigm(float x) { return 1.f / (1.f + __expf(-x)); }

__device__ inline void gll16(const void* g, void* l) {
    __builtin_amdgcn_global_load_lds((gvoid_t*)g, (lvoid_t*)l, 16, 0, 0);
}

// 16 L3-coherent (bypass L1+L2: sc0 sc1) 16B loads from the hi/lo h planes.
// hi loads issued first so vmcnt(8) releases the hi-pass MFMAs early.
#define GATHER_PLANES(H, L, HP, LP) \
  asm volatile( \
    "global_load_dwordx4 %0, %16, off sc0 sc1\n\t" \
    "global_load_dwordx4 %1, %16, off offset:64 sc0 sc1\n\t" \
    "global_load_dwordx4 %2, %16, off offset:128 sc0 sc1\n\t" \
    "global_load_dwordx4 %3, %16, off offset:192 sc0 sc1\n\t" \
    "global_load_dwordx4 %4, %16, off offset:256 sc0 sc1\n\t" \
    "global_load_dwordx4 %5, %16, off offset:320 sc0 sc1\n\t" \
    "global_load_dwordx4 %6, %16, off offset:384 sc0 sc1\n\t" \
    "global_load_dwordx4 %7, %16, off offset:448 sc0 sc1\n\t" \
    "global_load_dwordx4 %8, %17, off sc0 sc1\n\t" \
    "global_load_dwordx4 %9, %17, off offset:64 sc0 sc1\n\t" \
    "global_load_dwordx4 %10, %17, off offset:128 sc0 sc1\n\t" \
    "global_load_dwordx4 %11, %17, off offset:192 sc0 sc1\n\t" \
    "global_load_dwordx4 %12, %17, off offset:256 sc0 sc1\n\t" \
    "global_load_dwordx4 %13, %17, off offset:320 sc0 sc1\n\t" \
    "global_load_dwordx4 %14, %17, off offset:384 sc0 sc1\n\t" \
    "global_load_dwordx4 %15, %17, off offset:448 sc0 sc1" \
    : "=v"(H[0].u), "=v"(H[1].u), "=v"(H[2].u), "=v"(H[3].u), \
      "=v"(H[4].u), "=v"(H[5].u), "=v"(H[6].u), "=v"(H[7].u), \
      "=v"(L[0].u), "=v"(L[1].u), "=v"(L[2].u), "=v"(L[3].u), \
      "=v"(L[4].u), "=v"(L[5].u), "=v"(L[6].u), "=v"(L[7].u) \
    : "v"(HP), "v"(LP) : "memory")

__device__ inline void coh_store_u16(unsigned short* p, unsigned int v) {
    asm volatile("global_store_short %0, %1, off sc0 sc1" :: "v"(p), "v"(v) : "memory");
}
__device__ inline void coh_store_u32(int* p, int v) {
    asm volatile("global_store_dword %0, %1, off sc0 sc1" :: "v"(p), "v"(v) : "memory");
}
__device__ inline void plain_store_f32(float* p, float v) {
    asm volatile("global_store_dword %0, %1, off" :: "v"(p), "v"(v) : "memory");
}

// ---------- phase 0: fp32 -> bf16 converts / splits / counter zero ----------
__global__ void k_cvt(const float* __restrict__ s, unsigned short* __restrict__ d, int n4) {
    int i = blockIdx.x * blockDim.x + threadIdx.x;
    int st = gridDim.x * blockDim.x;
    for (; i < n4; i += st) {
        float4 v = ((const float4*)s)[i];
        ushort4 o;
        o.x = f2bf(v.x); o.y = f2bf(v.y); o.z = f2bf(v.z); o.w = f2bf(v.w);
        ((ushort4*)d)[i] = o;
    }
}

__global__ void k_split(const float* __restrict__ s, unsigned short* __restrict__ dh,
                        unsigned short* __restrict__ dl, int n4) {
    int i = blockIdx.x * blockDim.x + threadIdx.x;
    int st = gridDim.x * blockDim.x;
    for (; i < n4; i += st) {
        float4 v = ((const float4*)s)[i];
        ushort4 oh, ol;
        oh.x = f2bf(v.x); ol.x = f2bf(v.x - bf2f(oh.x));
        oh.y = f2bf(v.y); ol.y = f2bf(v.y - bf2f(oh.y));
        oh.z = f2bf(v.z); ol.z = f2bf(v.z - bf2f(oh.z));
        oh.w = f2bf(v.w); ol.w = f2bf(v.w - bf2f(oh.w));
        ((ushort4*)dh)[i] = oh;
        ((ushort4*)dl)[i] = ol;
    }
}

__global__ void k_zero(int* __restrict__ p) {
    int i = blockIdx.x * blockDim.x + threadIdx.x;
    if (i < 2048) p[i] = 0;
}

// ---------- phase 1: PI2 = x @ W_in^T + b_in, per-WG layout ----------
__global__ __launch_bounds__(256) void k_gemm_pi(const unsigned short* __restrict__ xb,
                                                 const unsigned short* __restrict__ wb,
                                                 const float* __restrict__ bin,
                                                 unsigned short* __restrict__ PI2) {
    __shared__ unsigned short sA[128 * 32];
    __shared__ unsigned short sB[128 * 32];
    const int tid = threadIdx.x;
    const int w = tid >> 6, l = tid & 63;
    const int wr = w >> 1, wc = w & 1;
    const long brow = (long)blockIdx.y * 128;
    const long bcol = (long)blockIdx.x * 128;

    f32x4 acc[4][4] = {};

    const int c0 = w * 128 + l;
    const int r0 = c0 >> 2, kc0 = (c0 & 3) * 8;
    const int c1 = c0 + 64;
    const int r1 = c1 >> 2, kc1 = (c1 & 3) * 8;
    unsigned short* lds0A = sA + (w * 128) * 8;
    unsigned short* lds1A = sA + (w * 128 + 64) * 8;
    unsigned short* lds0B = sB + (w * 128) * 8;
    unsigned short* lds1B = sB + (w * 128 + 64) * 8;

    const int frow = l & 15, kg = (l >> 4) * 8;

    for (int k0 = 0; k0 < DIN; k0 += 32) {
        __syncthreads();
        gll16(xb + (brow + r0) * DIN + k0 + kc0, lds0A);
        gll16(xb + (brow + r1) * DIN + k0 + kc1, lds1A);
        gll16(wb + (bcol + r0) * DIN + k0 + kc0, lds0B);
        gll16(wb + (bcol + r1) * DIN + k0 + kc1, lds1B);
        __syncthreads();
        bf16x8 aF[4], bF[4];
#pragma unroll
        for (int m = 0; m < 4; ++m)
            aF[m] = *(const bf16x8*)(sA + (wr * 64 + m * 16 + frow) * 32 + kg);
#pragma unroll
        for (int n = 0; n < 4; ++n)
            bF[n] = *(const bf16x8*)(sB + (wc * 64 + n * 16 + frow) * 32 + kg);
#pragma unroll
        for (int m = 0; m < 4; ++m)
#pragma unroll
            for (int n = 0; n < 4; ++n)
                acc[m][n] = __builtin_amdgcn_mfma_f32_16x16x32_bf16(aF[m], bF[n], acc[m][n], 0, 0, 0);
    }

#pragma unroll
    for (int m = 0; m < 4; ++m) {
#pragma unroll
        for (int n = 0; n < 4; ++n) {
            const long col = bcol + wc * 64 + n * 16 + (l & 15);
            const float bv = bin[col];
            const int g = (int)(col >> 9);
            const int cc = (int)(col & 511);
            const size_t base = (size_t)(cc >> 4) * PIWG + (size_t)(g * 16 + (cc & 15));
#pragma unroll
            for (int r = 0; r < 4; ++r) {
                const long row = brow + wr * 64 + m * 16 + (l >> 4) * 4 + r;
                PI2[base + (size_t)row * 96] = f2bf(acc[m][n][r] + bv);
            }
        }
    }
}

// ---------- phase 2: persistent recurrence, atomic-free flag barrier ----------
// 32 WGs x 256 thr. WG j owns h-columns [16j,16j+16). h = hi/lo ushort planes
// (parity double-buffered), sc0+sc1 (L3 coherence point). Barrier: counted
// vmcnt(4) drains ONLY the 4 h-publishes -> raw s_barrier -> one flag store
// per WG (own 128B line) -> wave0 gather-polls all 32 lines -> syncthreads.
__global__ __launch_bounds__(256, 1) void k_recur(
    const int* __restrict__ rel, const float* __restrict__ h0,
    const float* __restrict__ c0, const unsigned short* __restrict__ PI2,
    const unsigned short* __restrict__ wsh, const unsigned short* __restrict__ wsl,
    const float* __restrict__ bst, const float* __restrict__ drop,
    unsigned short* __restrict__ Hp, int* __restrict__ ctr, float* __restrict__ Hs)
{
    __shared__ unsigned short piB[2][4096];        // 16 KB PI slabs (dbuf, padded)
    __shared__ unsigned char relS[T_STEPS * BATCH];// 8 KB
    __shared__ unsigned long long pref[T_STEPS];   // 2 KB parity masks
    __shared__ float cS[NREL * 16];                // 3.25 KB c state
    __shared__ float red[2][2][5][256];            // 40 KB partial exchange
    __shared__ unsigned short Wlo[5120 * 8];       // 80 KB, per-lane-linear

    const int tid = threadIdx.x;
    const int w = tid >> 6, l = tid & 63;
    const int slot = blockIdx.x;
    const int hc0 = slot * 16;
    const unsigned short* slabBase = PI2 + (size_t)slot * PIWG;
    unsigned short* HpL = Hp + 2 * SREL;           // lo planes base
    int* myflag = ctr + slot * 32;                 // 128B-strided flag lines

    for (int i = tid; i < T_STEPS * BATCH; i += 256) relS[i] = (unsigned char)rel[i];
    __syncthreads();

    // per-step parity-prefix masks
    {
        unsigned long long f = 0;
        for (int b = 0; b < BATCH; ++b) f ^= 1ull << relS[tid * BATCH + b];
        pref[tid] = f;
    }
    __syncthreads();
    if (tid == 0) {
        unsigned long long run = 0;
        for (int t = 0; t < T_STEPS; ++t) {
            const unsigned long long f = pref[t];
            pref[t] = run;
            run ^= f;
        }
    }

    // W-lo -> LDS, per-lane-linear layout [kh][g][kk][lane] x 16B (no conflicts)
    for (int i = tid; i < 5120; i += 256) {
        const int kh2 = i / 2560, r2 = i % 2560;
        const int g2 = r2 / 512, r3 = r2 % 512;
        const int kk2 = r3 / 64, l2 = r3 % 64;
        const int fr2 = l2 & 15, ko2 = l2 >> 4;
        const bf16x8 v = *(const bf16x8*)(wsl + (size_t)(g2 * HD + hc0 + fr2) * HD
                                          + kh2 * 256 + kk2 * 32 + ko2 * 8);
        *(bf16x8*)(Wlo + (size_t)i * 8) = v;
    }

    const int m = w & 1, kh = w >> 1;
    const int frow = l & 15, koff = l >> 4;
    const int col = hc0 + frow;

    // W-hi slice -> registers (160 VGPR/thread)
    bf16x8 Wr[5][8];
#pragma unroll
    for (int g = 0; g < 5; ++g)
#pragma unroll
        for (int kk = 0; kk < 8; ++kk)
            Wr[g][kk] = *(const bf16x8*)(wsh + (size_t)(g * HD + hc0 + frow) * HD
                                         + kh * 256 + kk * 32 + koff * 8);

    // init c (LDS) and h parity-0 planes (coherent u16 stores)
    for (int i = tid; i < NREL * 16; i += 256) {
        const int r = i >> 4, c = hc0 + (i & 15);
        cS[i] = c0[r * HD + c];
        const float hv = h0[r * HD + c];
        const unsigned short hi = f2bf(hv);
        coh_store_u16(Hp + r * HD + c, hi);
        coh_store_u16(HpL + r * HD + c, (unsigned int)f2bf(hv - bf2f(hi)));
    }

    // preload PI slab 0 (uniform 2 gll16 per wave; overrun lands in pad)
    gll16(slabBase + (w * 64 + l) * 8, &piB[0][0] + (w * 64 + l) * 8);
    gll16(slabBase + (256 + w * 64 + l) * 8, &piB[0][0] + (256 + w * 64 + l) * 8);

    float bs0 = bst[col], bs1 = bst[HD + col], bs2 = bst[2 * HD + col];
    float bs3 = bst[3 * HD + col], bs4 = bst[4 * HD + col];
    const int rA = kh * 2, rB = rA + 1;            // this wave's gate rows
    const int bA = m * 16 + (l >> 4) * 4 + rA;
    const int bB = bA + 1;
    const float dropA = drop[bA * HD + col];
    const float dropB = drop[bB * HD + col];

    // initial barrier (full drain once)
    __syncthreads();
    asm volatile("s_waitcnt vmcnt(0)" ::: "memory");
    __builtin_amdgcn_s_barrier();
    if (tid == 0) coh_store_u32(myflag, 1);
    if (w == 0) {
        const int* fp = ctr + ((l < 32) ? l : 31) * 32;
        int fv, it = 0;
        do {
            asm volatile("global_load_dword %0, %1, off sc0 sc1\n\ts_waitcnt vmcnt(0)"
                         : "=v"(fv) : "v"(fp) : "memory");
        } while (!__all(fv >= 1) && ++it < SPIN_MAX);
    }
    __syncthreads();

    for (int t = 0; t < T_STEPS; ++t) {
        const unsigned long long pm = pref[t];

        // ---- gather this step's h fragments (hi first, then lo) ----
        const int id = relS[t * BATCH + m * 16 + frow];
        const unsigned short* hp = Hp + (int)((pm >> id) & 1) * SREL + id * HD + kh * 256 + koff * 8;
        const unsigned short* lp = hp + 2 * SREL;
        V16 hF[8], lF[8];
        GATHER_PLANES(hF, lF, hp, lp);
        asm volatile("s_waitcnt vmcnt(8)" ::: "memory");   // hi plane landed
        __builtin_amdgcn_sched_barrier(0);

        // ---- pass 1: h_hi * W_hi (overlaps lo-plane load tail) ----
        f32x4 acch[5] = {}, accl[5] = {}, accw[5] = {};
#pragma unroll
        for (int kk = 0; kk < 8; ++kk)
#pragma unroll
            for (int g = 0; g < 5; ++g)
                acch[g] = __builtin_amdgcn_mfma_f32_16x16x32_bf16(hF[kk].v, Wr[g][kk], acch[g], 0, 0, 0);

        asm volatile("s_waitcnt vmcnt(0)" ::: "memory");   // lo plane landed
        __builtin_amdgcn_sched_barrier(0);

        // ---- passes 2+3: h_lo * W_hi, h_hi * W_lo ----
#pragma unroll
        for (int kk = 0; kk < 8; ++kk)
#pragma unroll
            for (int g = 0; g < 5; ++g)
                accl[g] = __builtin_amdgcn_mfma_f32_16x16x32_bf16(lF[kk].v, Wr[g][kk], accl[g], 0, 0, 0);
#pragma unroll
        for (int kk = 0; kk < 8; ++kk)
#pragma unroll
            for (int g = 0; g < 5; ++g) {
                const bf16x8 wl = *(const bf16x8*)(Wlo + (size_t)((((kh * 5 + g) * 8 + kk) * 64) + l) * 8);
                accw[g] = __builtin_amdgcn_mfma_f32_16x16x32_bf16(hF[kk].v, wl, accw[g], 0, 0, 0);
            }

        // ---- symmetric partial exchange ----
#pragma unroll
        for (int g = 0; g < 5; ++g) {
            const f32x4 s = acch[g] + accl[g] + accw[g];
            *(f32x4*)&red[m][kh][g][l * 4] = s;
        }
        __syncthreads();   // red visible; drains this wave's PI DMA from t-1

        // ---- gates for this wave's 2 rows ----
        float hOutA, hOutB;
        int bAr, bBr;
        {
            float psA[5], psB[5];
#pragma unroll
            for (int g = 0; g < 5; ++g) {
                const f32x4 own = acch[g] + accl[g] + accw[g];
                const f32x4 oth = *(const f32x4*)&red[m][kh ^ 1][g][l * 4];
                psA[g] = own[rA] + oth[rA];
                psB[g] = own[rB] + oth[rB];
            }
            const unsigned short* pb = &piB[t & 1][0];
            const unsigned short* prA = pb + bA * 96 + frow;
            const unsigned short* prB = pb + bB * 96 + frow;
            const int idA = relS[t * BATCH + bA];
            const int idB = relS[t * BATCH + bB];
            bAr = idA; bBr = idB;
            {
                const float ig = sigm(bf2f(prA[0])  + psA[0] + bs0);
                const float fg = sigm(bf2f(prA[16]) + psA[1] + bs1);
                const float gg = tanhf(bf2f(prA[32]) + psA[2] + bs2);
                const float og = sigm(bf2f(prA[48]) + psA[3] + bs3);
                const float hw = sigm(bf2f(prA[64]) + psA[4] + bs4);
                const float cp = cS[idA * 16 + frow];
                const float cn = ig * gg + fg * cp;
                float h = og * tanhf(cn);
                h = hw * h + (1.f - hw) * bf2f(prA[80]);
                h *= dropA;
                cS[idA * 16 + frow] = cn;
                hOutA = h;
            }
            {
                const float ig = sigm(bf2f(prB[0])  + psB[0] + bs0);
                const float fg = sigm(bf2f(prB[16]) + psB[1] + bs1);
                const float gg = tanhf(bf2f(prB[32]) + psB[2] + bs2);
                const float og = sigm(bf2f(prB[48]) + psB[3] + bs3);
                const float hw = sigm(bf2f(prB[64]) + psB[4] + bs4);
                const float cp = cS[idB * 16 + frow];
                const float cn = ig * gg + fg * cp;
                float h = og * tanhf(cn);
                h = hw * h + (1.f - hw) * bf2f(prB[80]);
                h *= dropB;
                cS[idB * 16 + frow] = cn;
                hOutB = h;
            }
        }

        // ---- publishes (4) then Hs (2) then PI prefetch (2): exactly 8 VMEM ----
        {
            const unsigned short hhiA = f2bf(hOutA);
            const unsigned short hloA = f2bf(hOutA - bf2f(hhiA));
            const unsigned short hhiB = f2bf(hOutB);
            const unsigned short hloB = f2bf(hOutB - bf2f(hhiB));
            const int pwA = (int)(((pm >> bAr) & 1) ^ 1ull);
            const int pwB = (int)(((pm >> bBr) & 1) ^ 1ull);
            coh_store_u16(Hp + pwA * SREL + bAr * HD + col, hhiA);
            coh_store_u16(HpL + pwA * SREL + bAr * HD + col, hloA);
            coh_store_u16(Hp + pwB * SREL + bBr * HD + col, hhiB);
            coh_store_u16(HpL + pwB * SREL + bBr * HD + col, hloB);
            plain_store_f32(Hs + (size_t)(t * BATCH + bA) * HD + col, hOutA);
            plain_store_f32(Hs + (size_t)(t * BATCH + bB) * HD + col, hOutB);
            __builtin_amdgcn_sched_barrier(0);
            const int tn = (t + 1 < T_STEPS) ? (t + 1) : 0;
            const unsigned short* gsl = slabBase + (size_t)tn * 3072;
            unsigned short* dst = &piB[tn & 1][0];
            gll16(gsl + (w * 64 + l) * 8, dst + (w * 64 + l) * 8);
            gll16(gsl + (256 + w * 64 + l) * 8, dst + (256 + w * 64 + l) * 8);
            __builtin_amdgcn_sched_barrier(0);
        }

        // ---- counted drain: only the 4 publishes gate the barrier ----
        asm volatile("s_waitcnt vmcnt(4)" ::: "memory");
        __builtin_amdgcn_sched_barrier(0);
        __builtin_amdgcn_s_barrier();

        // ---- flag store + gather poll ----
        if (tid == 0) coh_store_u32(myflag, t + 2);
        if (w == 0) {
            const int* fp = ctr + ((l < 32) ? l : 31) * 32;
            int fv, it = 0;
            do {
                asm volatile("global_load_dword %0, %1, off sc0 sc1\n\ts_waitcnt vmcnt(0)"
                             : "=v"(fv) : "v"(fp) : "memory");
            } while (!__all(fv >= t + 2) && ++it < SPIN_MAX);
        }
        __syncthreads();
    }
}

// ---------- phase 3: preds = Hs @ W_out^T + b_out (fp32) ----------
__global__ __launch_bounds__(256) void k_pred(const float* __restrict__ Hs,
                                              const float* __restrict__ Wout,
                                              const float* __restrict__ bout,
                                              float* __restrict__ out) {
    __shared__ float hT[16 * HD];
    const int tid = threadIdx.x;
    const long row0 = (long)blockIdx.x * 16;
    for (int i = tid; i < (16 * HD) / 4; i += 256)
        ((float4*)hT)[i] = ((const float4*)(Hs + row0 * HD))[i];
    __syncthreads();
    const int w = tid >> 6, c = tid & 63;
    if (c < NREL) {
        float a0 = bout[c], a1 = a0, a2 = a0, a3 = a0;
        const float* wrp = Wout + c * HD;
        for (int k = 0; k < HD; k += 4) {
            const float4 wv = *(const float4*)(wrp + k);
            const float4 h0 = *(const float4*)(hT + (w * 4 + 0) * HD + k);
            const float4 h1 = *(const float4*)(hT + (w * 4 + 1) * HD + k);
            const float4 h2 = *(const float4*)(hT + (w * 4 + 2) * HD + k);
            const float4 h3 = *(const float4*)(hT + (w * 4 + 3) * HD + k);
            a0 += wv.x * h0.x + wv.y * h0.y + wv.z * h0.z + wv.w * h0.w;
            a1 += wv.x * h1.x + wv.y * h1.y + wv.z * h1.z + wv.w * h1.w;
            a2 += wv.x * h2.x + wv.y * h2.y + wv.z * h2.z + wv.w * h2.w;
            a3 += wv.x * h3.x + wv.y * h3.y + wv.z * h3.z + wv.w * h3.w;
        }
        out[(row0 + w * 4 + 0) * NREL + c] = a0;
        out[(row0 + w * 4 + 1) * NREL + c] = a1;
        out[(row0 + w * 4 + 2) * NREL + c] = a2;
        out[(row0 + w * 4 + 3) * NREL + c] = a3;
    }
}

extern "C" void kernel_launch(void* const* d_in, const int* in_sizes, int n_in,
                              void* d_out, int out_size, void* d_ws, size_t ws_size,
                              hipStream_t stream) {
    const float* x    = (const float*)d_in[0];
    const int*   rel  = (const int*)  d_in[1];
    const float* h0   = (const float*)d_in[2];
    const float* c0   = (const float*)d_in[3];
    const float* Win  = (const float*)d_in[4];
    const float* bin  = (const float*)d_in[5];
    const float* Wst  = (const float*)d_in[6];
    const float* bst  = (const float*)d_in[7];
    const float* Wout = (const float*)d_in[8];
    const float* bout = (const float*)d_in[9];
    const float* drop = (const float*)d_in[10];

    char* ws = (char*)d_ws;
    // workspace layout (bytes), total ~164.9 MB
    unsigned short* xb  = (unsigned short*)(ws);              // 67,108,864
    unsigned short* wb  = (unsigned short*)(ws + 67108864);   // 25,165,824
    unsigned short* wsh = (unsigned short*)(ws + 92274688);   //  2,621,440
    unsigned short* wsl = (unsigned short*)(ws + 94896128);   //  2,621,440
    unsigned short* PI2 = (unsigned short*)(ws + 97517568);   // 50,331,648
    unsigned short* Hp  = (unsigned short*)(ws + 147849216);  //    208,896 (hi/lo x 2 parity)
    float*          Hs  = (float*)         (ws + 148058112);  // 16,777,216
    int*            ctr = (int*)           (ws + 164835328);  //      8,192
    float* out = (float*)d_out;

    k_zero<<<8, 256, 0, stream>>>(ctr);
    k_cvt<<<2048, 256, 0, stream>>>(x, xb, (TB * DIN) / 4);
    k_cvt<<<1024, 256, 0, stream>>>(Win, wb, (SIXH * DIN) / 4);
    k_split<<<320, 256, 0, stream>>>(Wst, wsh, wsl, (FIVEH * HD) / 4);

    k_gemm_pi<<<dim3(SIXH / 128, TB / 128), 256, 0, stream>>>(xb, wb, bin, PI2);

    k_recur<<<32, 256, 0, stream>>>(rel, h0, c0, PI2, wsh, wsl, bst, drop, Hp, ctr, Hs);

    k_pred<<<512, 256, 0, stream>>>(Hs, Wout, bout, out);
}

// Round 11
// 1610.613 us; speedup vs baseline: 1.5950x; 1.2138x over previous
//
#include <hip/hip_runtime.h>
#include <stdint.h>

#define T_STEPS 256
#define BATCH   32
#define DIN     4096
#define HD      512
#define NREL    51
#define TB      8192      // T*B
#define SIXH    3072
#define FIVEH   2560
#define SREL    (NREL * HD)
#define PIWG    786432    // per-WG PI2 block (elems) = TB*6*16
#define SPIN_MAX (1 << 18)

typedef short bf16x8 __attribute__((ext_vector_type(8)));
typedef float f32x4  __attribute__((ext_vector_type(4)));
typedef unsigned int u32x4 __attribute__((ext_vector_type(4)));

union V16 { u32x4 u; bf16x8 v; };

typedef __attribute__((address_space(1))) const void gvoid_t;
typedef __attribute__((address_space(3))) void lvoid_t;

__device__ inline float bf2f(unsigned short u) {
    return __uint_as_float(((unsigned int)u) << 16);
}
__device__ inline unsigned short f2bf(float f) {
    unsigned int x = __float_as_uint(f);
    x += 0x7fffu + ((x >> 16) & 1u);   // RNE
    return (unsigned short)(x >> 16);
}
// fast gate activations: v_exp + v_rcp (1-ulp), saturate correctly at +-inf
__device__ inline float sigm(float x) {
    return __builtin_amdgcn_rcpf(1.f + __expf(-x));
}
__device__ inline float tanh_fast(float x) {
    return 1.f - 2.f * __builtin_amdgcn_rcpf(1.f + __expf(2.f * x));
}

__device__ inline void gll16(const void* g, void* l) {
    __builtin_amdgcn_global_load_lds((gvoid_t*)g, (lvoid_t*)l, 16, 0, 0);
}

// 16 L2-bypass (sc0 sc1 -> L3 coherence point) 16B loads from hi/lo h planes.
// hi loads first so vmcnt(8) releases the hi-pass MFMAs early.
#define GATHER_PLANES(H, L, HP, LP) \
  asm volatile( \
    "global_load_dwordx4 %0, %16, off sc0 sc1\n\t" \
    "global_load_dwordx4 %1, %16, off offset:64 sc0 sc1\n\t" \
    "global_load_dwordx4 %2, %16, off offset:128 sc0 sc1\n\t" \
    "global_load_dwordx4 %3, %16, off offset:192 sc0 sc1\n\t" \
    "global_load_dwordx4 %4, %16, off offset:256 sc0 sc1\n\t" \
    "global_load_dwordx4 %5, %16, off offset:320 sc0 sc1\n\t" \
    "global_load_dwordx4 %6, %16, off offset:384 sc0 sc1\n\t" \
    "global_load_dwordx4 %7, %16, off offset:448 sc0 sc1\n\t" \
    "global_load_dwordx4 %8, %17, off sc0 sc1\n\t" \
    "global_load_dwordx4 %9, %17, off offset:64 sc0 sc1\n\t" \
    "global_load_dwordx4 %10, %17, off offset:128 sc0 sc1\n\t" \
    "global_load_dwordx4 %11, %17, off offset:192 sc0 sc1\n\t" \
    "global_load_dwordx4 %12, %17, off offset:256 sc0 sc1\n\t" \
    "global_load_dwordx4 %13, %17, off offset:320 sc0 sc1\n\t" \
    "global_load_dwordx4 %14, %17, off offset:384 sc0 sc1\n\t" \
    "global_load_dwordx4 %15, %17, off offset:448 sc0 sc1" \
    : "=v"(H[0].u), "=v"(H[1].u), "=v"(H[2].u), "=v"(H[3].u), \
      "=v"(H[4].u), "=v"(H[5].u), "=v"(H[6].u), "=v"(H[7].u), \
      "=v"(L[0].u), "=v"(L[1].u), "=v"(L[2].u), "=v"(L[3].u), \
      "=v"(L[4].u), "=v"(L[5].u), "=v"(L[6].u), "=v"(L[7].u) \
    : "v"(HP), "v"(LP) : "memory")

__device__ inline void coh_store_u16(unsigned short* p, unsigned int v) {
    asm volatile("global_store_short %0, %1, off sc0 sc1" :: "v"(p), "v"(v) : "memory");
}
__device__ inline void coh_store_u32(int* p, int v) {
    asm volatile("global_store_dword %0, %1, off sc0 sc1" :: "v"(p), "v"(v) : "memory");
}
__device__ inline void plain_store_f32(float* p, float v) {
    asm volatile("global_store_dword %0, %1, off" :: "v"(p), "v"(v) : "memory");
}

// ---------- phase 0: fp32 -> bf16 converts / counter zero ----------
__global__ void k_cvt(const float* __restrict__ s, unsigned short* __restrict__ d, int n4) {
    int i = blockIdx.x * blockDim.x + threadIdx.x;
    int st = gridDim.x * blockDim.x;
    for (; i < n4; i += st) {
        float4 v = ((const float4*)s)[i];
        ushort4 o;
        o.x = f2bf(v.x); o.y = f2bf(v.y); o.z = f2bf(v.z); o.w = f2bf(v.w);
        ((ushort4*)d)[i] = o;
    }
}

__global__ void k_zero(int* __restrict__ p) {
    int i = blockIdx.x * blockDim.x + threadIdx.x;
    if (i < 2048) p[i] = 0;
}

// ---------- phase 1: PI2 = x @ W_in^T + b_in, per-WG layout ----------
__global__ __launch_bounds__(256) void k_gemm_pi(const unsigned short* __restrict__ xb,
                                                 const unsigned short* __restrict__ wb,
                                                 const float* __restrict__ bin,
                                                 unsigned short* __restrict__ PI2) {
    __shared__ unsigned short sA[128 * 32];
    __shared__ unsigned short sB[128 * 32];
    const int tid = threadIdx.x;
    const int w = tid >> 6, l = tid & 63;
    const int wr = w >> 1, wc = w & 1;
    const long brow = (long)blockIdx.y * 128;
    const long bcol = (long)blockIdx.x * 128;

    f32x4 acc[4][4] = {};

    const int c0 = w * 128 + l;
    const int r0 = c0 >> 2, kc0 = (c0 & 3) * 8;
    const int c1 = c0 + 64;
    const int r1 = c1 >> 2, kc1 = (c1 & 3) * 8;
    unsigned short* lds0A = sA + (w * 128) * 8;
    unsigned short* lds1A = sA + (w * 128 + 64) * 8;
    unsigned short* lds0B = sB + (w * 128) * 8;
    unsigned short* lds1B = sB + (w * 128 + 64) * 8;

    const int frow = l & 15, kg = (l >> 4) * 8;

    for (int k0 = 0; k0 < DIN; k0 += 32) {
        __syncthreads();
        gll16(xb + (brow + r0) * DIN + k0 + kc0, lds0A);
        gll16(xb + (brow + r1) * DIN + k0 + kc1, lds1A);
        gll16(wb + (bcol + r0) * DIN + k0 + kc0, lds0B);
        gll16(wb + (bcol + r1) * DIN + k0 + kc1, lds1B);
        __syncthreads();
        bf16x8 aF[4], bF[4];
#pragma unroll
        for (int m = 0; m < 4; ++m)
            aF[m] = *(const bf16x8*)(sA + (wr * 64 + m * 16 + frow) * 32 + kg);
#pragma unroll
        for (int n = 0; n < 4; ++n)
            bF[n] = *(const bf16x8*)(sB + (wc * 64 + n * 16 + frow) * 32 + kg);
#pragma unroll
        for (int m = 0; m < 4; ++m)
#pragma unroll
            for (int n = 0; n < 4; ++n)
                acc[m][n] = __builtin_amdgcn_mfma_f32_16x16x32_bf16(aF[m], bF[n], acc[m][n], 0, 0, 0);
    }

#pragma unroll
    for (int m = 0; m < 4; ++m) {
#pragma unroll
        for (int n = 0; n < 4; ++n) {
            const long col = bcol + wc * 64 + n * 16 + (l & 15);
            const float bv = bin[col];
            const int g = (int)(col >> 9);
            const int cc = (int)(col & 511);
            const size_t base = (size_t)(cc >> 4) * PIWG + (size_t)(g * 16 + (cc & 15));
#pragma unroll
            for (int r = 0; r < 4; ++r) {
                const long row = brow + wr * 64 + m * 16 + (l >> 4) * 4 + r;
                PI2[base + (size_t)row * 96] = f2bf(acc[m][n][r] + bv);
            }
        }
    }
}

// ---------- phase 2: persistent recurrence, atomic-free flag barrier ----------
// 32 WGs x 256 thr. WG j owns h-columns [16j,16j+16). h = hi/lo ushort planes
// (parity double-buffered), sc0+sc1 (L3 coherence point). 2 MFMA passes
// (h_hi*W, h_lo*W). Barrier: vmcnt(4) drains only the 4 h-publishes ->
// s_barrier -> wave1 stores flag -> wave0 gather-polls 32 lines -> release.
__global__ __launch_bounds__(256, 1) void k_recur(
    const int* __restrict__ rel, const float* __restrict__ h0,
    const float* __restrict__ c0, const unsigned short* __restrict__ PI2,
    const unsigned short* __restrict__ wsb,
    const float* __restrict__ bst, const float* __restrict__ drop,
    unsigned short* __restrict__ Hp, int* __restrict__ ctr, float* __restrict__ Hs)
{
    __shared__ unsigned short piB[2][4096];        // 16 KB PI slabs (dbuf, padded)
    __shared__ unsigned char relS[T_STEPS * BATCH];// 8 KB
    __shared__ unsigned long long pref[T_STEPS];   // 2 KB parity masks
    __shared__ float cS[NREL * 16];                // 3.25 KB c state
    __shared__ float red[2][2][5][256];            // 40 KB partial exchange
    __shared__ float pad1[4096];                   // 16 KB pad -> force 1 WG/CU
    __shared__ float pad2[1024];                   //  4 KB pad (total ~89 KB)

    const int tid = threadIdx.x;
    const int w = tid >> 6, l = tid & 63;
    const int slot = blockIdx.x;
    const int hc0 = slot * 16;
    const unsigned short* slabBase = PI2 + (size_t)slot * PIWG;
    unsigned short* HpL = Hp + 2 * SREL;           // lo planes base
    int* myflag = ctr + slot * 32;                 // 128B-strided flag lines

    for (int i = tid; i < T_STEPS * BATCH; i += 256) relS[i] = (unsigned char)rel[i];
    __syncthreads();
    if (relS[0] == 255) { pad1[tid] = 1.f; pad2[tid & 1023] = pad1[255 - tid]; cS[0] = pad2[0]; }

    // per-step parity-prefix masks
    {
        unsigned long long f = 0;
        for (int b = 0; b < BATCH; ++b) f ^= 1ull << relS[tid * BATCH + b];
        pref[tid] = f;
    }
    __syncthreads();
    if (tid == 0) {
        unsigned long long run = 0;
        for (int t = 0; t < T_STEPS; ++t) {
            const unsigned long long f = pref[t];
            pref[t] = run;
            run ^= f;
        }
    }

    const int m = w & 1, kh = w >> 1;
    const int frow = l & 15, koff = l >> 4;
    const int col = hc0 + frow;

    // W slice -> registers (160 VGPR/thread; unified file budget 512 @1 wave/SIMD)
    bf16x8 Wr[5][8];
#pragma unroll
    for (int g = 0; g < 5; ++g)
#pragma unroll
        for (int kk = 0; kk < 8; ++kk)
            Wr[g][kk] = *(const bf16x8*)(wsb + (size_t)(g * HD + hc0 + frow) * HD
                                         + kh * 256 + kk * 32 + koff * 8);

    // init c (LDS) and h parity-0 planes (coherent u16 stores)
    for (int i = tid; i < NREL * 16; i += 256) {
        const int r = i >> 4, c = hc0 + (i & 15);
        cS[i] = c0[r * HD + c];
        const float hv = h0[r * HD + c];
        const unsigned short hi = f2bf(hv);
        coh_store_u16(Hp + r * HD + c, hi);
        coh_store_u16(HpL + r * HD + c, (unsigned int)f2bf(hv - bf2f(hi)));
    }

    // preload PI slab 0 (uniform 2 gll16 per thread; overrun lands in pad)
    gll16(slabBase + (w * 64 + l) * 8, &piB[0][0] + (w * 64 + l) * 8);
    gll16(slabBase + (256 + w * 64 + l) * 8, &piB[0][0] + (256 + w * 64 + l) * 8);

    float bs0 = bst[col], bs1 = bst[HD + col], bs2 = bst[2 * HD + col];
    float bs3 = bst[3 * HD + col], bs4 = bst[4 * HD + col];
    const int rA = kh * 2, rB = rA + 1;            // this wave's gate rows
    const int bA = m * 16 + (l >> 4) * 4 + rA;
    const int bB = bA + 1;
    const float dropA = drop[bA * HD + col];
    const float dropB = drop[bB * HD + col];

    // initial barrier (full drain once)
    __syncthreads();
    asm volatile("s_waitcnt vmcnt(0)" ::: "memory");
    __builtin_amdgcn_s_barrier();
    if (tid == 64) coh_store_u32(myflag, 1);
    if (w == 0) {
        const int* fp = ctr + ((l < 32) ? l : 31) * 32;
        int fv, it = 0;
        do {
            asm volatile("global_load_dword %0, %1, off sc0 sc1\n\ts_waitcnt vmcnt(0)"
                         : "=v"(fv) : "v"(fp) : "memory");
        } while (!__all(fv >= 1) && ++it < SPIN_MAX);
    }
    __syncthreads();

    for (int t = 0; t < T_STEPS; ++t) {
        const unsigned long long pm = pref[t];

        // ---- gather this step's h fragments (hi first, then lo) ----
        const int id = relS[t * BATCH + m * 16 + frow];
        const unsigned short* hp = Hp + (int)((pm >> id) & 1) * SREL + id * HD + kh * 256 + koff * 8;
        const unsigned short* lp = hp + 2 * SREL;
        V16 hF[8], lF[8];
        GATHER_PLANES(hF, lF, hp, lp);
        asm volatile("s_waitcnt vmcnt(8)" ::: "memory");   // hi plane landed
        __builtin_amdgcn_sched_barrier(0);

        // ---- pass 1: h_hi * W (overlaps lo-plane load tail) ----
        f32x4 acch[5] = {}, accl[5] = {};
#pragma unroll
        for (int kk = 0; kk < 8; ++kk)
#pragma unroll
            for (int g = 0; g < 5; ++g)
                acch[g] = __builtin_amdgcn_mfma_f32_16x16x32_bf16(hF[kk].v, Wr[g][kk], acch[g], 0, 0, 0);

        asm volatile("s_waitcnt vmcnt(0)" ::: "memory");   // lo plane landed
        __builtin_amdgcn_sched_barrier(0);

        // ---- pass 2: h_lo * W ----
#pragma unroll
        for (int kk = 0; kk < 8; ++kk)
#pragma unroll
            for (int g = 0; g < 5; ++g)
                accl[g] = __builtin_amdgcn_mfma_f32_16x16x32_bf16(lF[kk].v, Wr[g][kk], accl[g], 0, 0, 0);

        // ---- symmetric partial exchange (own sums kept in regs) ----
        f32x4 own[5];
#pragma unroll
        for (int g = 0; g < 5; ++g) {
            own[g] = acch[g] + accl[g];
            *(f32x4*)&red[m][kh][g][l * 4] = own[g];
        }
        __syncthreads();   // red visible; drains this wave's PI DMA from t-1

        // ---- gates for this wave's 2 rows ----
        float hOutA, hOutB;
        int bAr, bBr;
        {
            float psA[5], psB[5];
#pragma unroll
            for (int g = 0; g < 5; ++g) {
                const f32x4 oth = *(const f32x4*)&red[m][kh ^ 1][g][l * 4];
                psA[g] = own[g][rA] + oth[rA];
                psB[g] = own[g][rB] + oth[rB];
            }
            const unsigned short* pb = &piB[t & 1][0];
            const unsigned short* prA = pb + bA * 96 + frow;
            const unsigned short* prB = pb + bB * 96 + frow;
            const int idA = relS[t * BATCH + bA];
            const int idB = relS[t * BATCH + bB];
            bAr = idA; bBr = idB;
            {
                const float ig = sigm(bf2f(prA[0])  + psA[0] + bs0);
                const float fg = sigm(bf2f(prA[16]) + psA[1] + bs1);
                const float gg = tanh_fast(bf2f(prA[32]) + psA[2] + bs2);
                const float og = sigm(bf2f(prA[48]) + psA[3] + bs3);
                const float hw = sigm(bf2f(prA[64]) + psA[4] + bs4);
                const float cp = cS[idA * 16 + frow];
                const float cn = ig * gg + fg * cp;
                float h = og * tanh_fast(cn);
                h = hw * h + (1.f - hw) * bf2f(prA[80]);
                h *= dropA;
                cS[idA * 16 + frow] = cn;
                hOutA = h;
            }
            {
                const float ig = sigm(bf2f(prB[0])  + psB[0] + bs0);
                const float fg = sigm(bf2f(prB[16]) + psB[1] + bs1);
                const float gg = tanh_fast(bf2f(prB[32]) + psB[2] + bs2);
                const float og = sigm(bf2f(prB[48]) + psB[3] + bs3);
                const float hw = sigm(bf2f(prB[64]) + psB[4] + bs4);
                const float cp = cS[idB * 16 + frow];
                const float cn = ig * gg + fg * cp;
                float h = og * tanh_fast(cn);
                h = hw * h + (1.f - hw) * bf2f(prB[80]);
                h *= dropB;
                cS[idB * 16 + frow] = cn;
                hOutB = h;
            }
        }

        // ---- publishes (4) then Hs (2) then PI prefetch (2): exactly 8 VMEM ----
        {
            const unsigned short hhiA = f2bf(hOutA);
            const unsigned short hloA = f2bf(hOutA - bf2f(hhiA));
            const unsigned short hhiB = f2bf(hOutB);
            const unsigned short hloB = f2bf(hOutB - bf2f(hhiB));
            const int pwA = (int)(((pm >> bAr) & 1) ^ 1ull);
            const int pwB = (int)(((pm >> bBr) & 1) ^ 1ull);
            coh_store_u16(Hp + pwA * SREL + bAr * HD + col, hhiA);
            coh_store_u16(HpL + pwA * SREL + bAr * HD + col, hloA);
            coh_store_u16(Hp + pwB * SREL + bBr * HD + col, hhiB);
            coh_store_u16(HpL + pwB * SREL + bBr * HD + col, hloB);
            plain_store_f32(Hs + (size_t)(t * BATCH + bA) * HD + col, hOutA);
            plain_store_f32(Hs + (size_t)(t * BATCH + bB) * HD + col, hOutB);
            __builtin_amdgcn_sched_barrier(0);
            const int tn = (t + 1 < T_STEPS) ? (t + 1) : 0;
            const unsigned short* gsl = slabBase + (size_t)tn * 3072;
            unsigned short* dst = &piB[tn & 1][0];
            gll16(gsl + (w * 64 + l) * 8, dst + (w * 64 + l) * 8);
            gll16(gsl + (256 + w * 64 + l) * 8, dst + (256 + w * 64 + l) * 8);
            __builtin_amdgcn_sched_barrier(0);
        }

        // ---- counted drain: only the 4 publishes gate the barrier ----
        asm volatile("s_waitcnt vmcnt(4)" ::: "memory");
        __builtin_amdgcn_sched_barrier(0);
        __builtin_amdgcn_s_barrier();

        // ---- flag store (wave 1) + gather poll (wave 0) ----
        if (tid == 64) coh_store_u32(myflag, t + 2);
        if (w == 0) {
            const int* fp = ctr + ((l < 32) ? l : 31) * 32;
            int fv, it = 0;
            do {
                asm volatile("global_load_dword %0, %1, off sc0 sc1\n\ts_waitcnt vmcnt(0)"
                             : "=v"(fv) : "v"(fp) : "memory");
            } while (!__all(fv >= t + 2) && ++it < SPIN_MAX);
        }
        __syncthreads();
    }
}

// ---------- phase 3: preds = Hs @ W_out^T + b_out (fp32) ----------
__global__ __launch_bounds__(256) void k_pred(const float* __restrict__ Hs,
                                              const float* __restrict__ Wout,
                                              const float* __restrict__ bout,
                                              float* __restrict__ out) {
    __shared__ float hT[16 * HD];
    const int tid = threadIdx.x;
    const long row0 = (long)blockIdx.x * 16;
    for (int i = tid; i < (16 * HD) / 4; i += 256)
        ((float4*)hT)[i] = ((const float4*)(Hs + row0 * HD))[i];
    __syncthreads();
    const int w = tid >> 6, c = tid & 63;
    if (c < NREL) {
        float a0 = bout[c], a1 = a0, a2 = a0, a3 = a0;
        const float* wrp = Wout + c * HD;
        for (int k = 0; k < HD; k += 4) {
            const float4 wv = *(const float4*)(wrp + k);
            const float4 h0 = *(const float4*)(hT + (w * 4 + 0) * HD + k);
            const float4 h1 = *(const float4*)(hT + (w * 4 + 1) * HD + k);
            const float4 h2 = *(const float4*)(hT + (w * 4 + 2) * HD + k);
            const float4 h3 = *(const float4*)(hT + (w * 4 + 3) * HD + k);
            a0 += wv.x * h0.x + wv.y * h0.y + wv.z * h0.z + wv.w * h0.w;
            a1 += wv.x * h1.x + wv.y * h1.y + wv.z * h1.z + wv.w * h1.w;
            a2 += wv.x * h2.x + wv.y * h2.y + wv.z * h2.z + wv.w * h2.w;
            a3 += wv.x * h3.x + wv.y * h3.y + wv.z * h3.z + wv.w * h3.w;
        }
        out[(row0 + w * 4 + 0) * NREL + c] = a0;
        out[(row0 + w * 4 + 1) * NREL + c] = a1;
        out[(row0 + w * 4 + 2) * NREL + c] = a2;
        out[(row0 + w * 4 + 3) * NREL + c] = a3;
    }
}

extern "C" void kernel_launch(void* const* d_in, const int* in_sizes, int n_in,
                              void* d_out, int out_size, void* d_ws, size_t ws_size,
                              hipStream_t stream) {
    const float* x    = (const float*)d_in[0];
    const int*   rel  = (const int*)  d_in[1];
    const float* h0   = (const float*)d_in[2];
    const float* c0   = (const float*)d_in[3];
    const float* Win  = (const float*)d_in[4];
    const float* bin  = (const float*)d_in[5];
    const float* Wst  = (const float*)d_in[6];
    const float* bst  = (const float*)d_in[7];
    const float* Wout = (const float*)d_in[8];
    const float* bout = (const float*)d_in[9];
    const float* drop = (const float*)d_in[10];

    char* ws = (char*)d_ws;
    // workspace layout (bytes), total ~162.3 MB
    unsigned short* xb  = (unsigned short*)(ws);              // 67,108,864
    unsigned short* wb  = (unsigned short*)(ws + 67108864);   // 25,165,824
    unsigned short* wsb = (unsigned short*)(ws + 92274688);   //  2,621,440
    unsigned short* PI2 = (unsigned short*)(ws + 94896128);   // 50,331,648
    unsigned short* Hp  = (unsigned short*)(ws + 145227776);  //    208,896 (hi/lo x 2 parity)
    float*          Hs  = (float*)         (ws + 145436672);  // 16,777,216
    int*            ctr = (int*)           (ws + 162213888);  //      8,192
    float* out = (float*)d_out;

    k_zero<<<8, 256, 0, stream>>>(ctr);
    k_cvt<<<2048, 256, 0, stream>>>(x, xb, (TB * DIN) / 4);
    k_cvt<<<1024, 256, 0, stream>>>(Win, wb, (SIXH * DIN) / 4);
    k_cvt<<<320, 256, 0, stream>>>(Wst, wsb, (FIVEH * HD) / 4);

    k_gemm_pi<<<dim3(SIXH / 128, TB / 128), 256, 0, stream>>>(xb, wb, bin, PI2);

    k_recur<<<32, 256, 0, stream>>>(rel, h0, c0, PI2, wsb, bst, drop, Hp, ctr, Hs);

    k_pred<<<512, 256, 0, stream>>>(Hs, Wout, bout, out);
}

// Round 12
// 1557.733 us; speedup vs baseline: 1.6491x; 1.0339x over previous
//
#include <hip/hip_runtime.h>
#include <stdint.h>

#define T_STEPS 256
#define BATCH   32
#define DIN     4096
#define HD      512
#define NREL    51
#define TB      8192      // T*B
#define SIXH    3072
#define FIVEH   2560
#define SREL    (NREL * HD)
#define PIWG    786432    // per-WG PI2 block (elems) = TB*6*16
#define NTILES  1536      // (TB/128) * (SIXH/128)
#define GWGS    224
#define SPIN_MAX (1 << 18)

typedef short bf16x8 __attribute__((ext_vector_type(8)));
typedef float f32x4  __attribute__((ext_vector_type(4)));
typedef unsigned int u32x4 __attribute__((ext_vector_type(4)));

union V16 { u32x4 u; bf16x8 v; };

typedef __attribute__((address_space(1))) const void gvoid_t;
typedef __attribute__((address_space(3))) void lvoid_t;

__device__ inline float bf2f(unsigned short u) {
    return __uint_as_float(((unsigned int)u) << 16);
}
__device__ inline unsigned short f2bf(float f) {
    unsigned int x = __float_as_uint(f);
    x += 0x7fffu + ((x >> 16) & 1u);   // RNE
    return (unsigned short)(x >> 16);
}
__device__ inline float sigm(float x) {
    return __builtin_amdgcn_rcpf(1.f + __expf(-x));
}
__device__ inline float tanh_fast(float x) {
    return 1.f - 2.f * __builtin_amdgcn_rcpf(1.f + __expf(2.f * x));
}

__device__ inline void gll16(const void* g, void* l) {
    __builtin_amdgcn_global_load_lds((gvoid_t*)g, (lvoid_t*)l, 16, 0, 0);
}

// 16 L2-bypass (sc0 sc1 -> L3 coherence point) 16B loads from hi/lo h planes.
#define GATHER_PLANES(H, L, HP, LP) \
  asm volatile( \
    "global_load_dwordx4 %0, %16, off sc0 sc1\n\t" \
    "global_load_dwordx4 %1, %16, off offset:64 sc0 sc1\n\t" \
    "global_load_dwordx4 %2, %16, off offset:128 sc0 sc1\n\t" \
    "global_load_dwordx4 %3, %16, off offset:192 sc0 sc1\n\t" \
    "global_load_dwordx4 %4, %16, off offset:256 sc0 sc1\n\t" \
    "global_load_dwordx4 %5, %16, off offset:320 sc0 sc1\n\t" \
    "global_load_dwordx4 %6, %16, off offset:384 sc0 sc1\n\t" \
    "global_load_dwordx4 %7, %16, off offset:448 sc0 sc1\n\t" \
    "global_load_dwordx4 %8, %17, off sc0 sc1\n\t" \
    "global_load_dwordx4 %9, %17, off offset:64 sc0 sc1\n\t" \
    "global_load_dwordx4 %10, %17, off offset:128 sc0 sc1\n\t" \
    "global_load_dwordx4 %11, %17, off offset:192 sc0 sc1\n\t" \
    "global_load_dwordx4 %12, %17, off offset:256 sc0 sc1\n\t" \
    "global_load_dwordx4 %13, %17, off offset:320 sc0 sc1\n\t" \
    "global_load_dwordx4 %14, %17, off offset:384 sc0 sc1\n\t" \
    "global_load_dwordx4 %15, %17, off offset:448 sc0 sc1" \
    : "=v"(H[0].u), "=v"(H[1].u), "=v"(H[2].u), "=v"(H[3].u), \
      "=v"(H[4].u), "=v"(H[5].u), "=v"(H[6].u), "=v"(H[7].u), \
      "=v"(L[0].u), "=v"(L[1].u), "=v"(L[2].u), "=v"(L[3].u), \
      "=v"(L[4].u), "=v"(L[5].u), "=v"(L[6].u), "=v"(L[7].u) \
    : "v"(HP), "v"(LP) : "memory")

__device__ inline void coh_store_u16(unsigned short* p, unsigned int v) {
    asm volatile("global_store_short %0, %1, off sc0 sc1" :: "v"(p), "v"(v) : "memory");
}
__device__ inline void coh_store_u32(int* p, int v) {
    asm volatile("global_store_dword %0, %1, off sc0 sc1" :: "v"(p), "v"(v) : "memory");
}
__device__ inline void plain_store_f32(float* p, float v) {
    asm volatile("global_store_dword %0, %1, off" :: "v"(p), "v"(v) : "memory");
}
__device__ inline int coh_load_i32(const int* p) {
    int v;
    asm volatile("global_load_dword %0, %1, off sc0 sc1\n\ts_waitcnt vmcnt(0)"
                 : "=v"(v) : "v"(p) : "memory");
    return v;
}

// ---------- phase 0: fp32 -> bf16 converts / control zero ----------
__global__ void k_cvt(const float* __restrict__ s, unsigned short* __restrict__ d, int n4) {
    int i = blockIdx.x * blockDim.x + threadIdx.x;
    int st = gridDim.x * blockDim.x;
    for (; i < n4; i += st) {
        float4 v = ((const float4*)s)[i];
        ushort4 o;
        o.x = f2bf(v.x); o.y = f2bf(v.y); o.z = f2bf(v.z); o.w = f2bf(v.w);
        ((ushort4*)d)[i] = o;
    }
}

__global__ void k_zero(int* __restrict__ p) {
    int i = blockIdx.x * blockDim.x + threadIdx.x;
    if (i < 2048) p[i] = 0;
}

// ---------- fused kernel: WGs 0-31 recurrence, WGs 32-255 PI GEMM ----------
// 256 WGs x 256 thr, 1 WG/CU (85 KB LDS). GEMM sweeps tiles row-block-major,
// publishes done[by] via sc0sc1 stores + vmcnt(0) + device atomicAdd (same
// discipline as the proven h-path). Recurrence gates slab prefetch on
// done[(t+1)>>2] >= 24 (poll every 4 steps until done[63] shortcut fires).
__global__ __launch_bounds__(256, 1) void k_main(
    const int* __restrict__ rel, const float* __restrict__ h0,
    const float* __restrict__ c0, unsigned short* __restrict__ PI2,
    const unsigned short* __restrict__ wsb,
    const float* __restrict__ bst, const float* __restrict__ drop,
    unsigned short* __restrict__ Hp, int* __restrict__ ctr, float* __restrict__ Hs,
    const unsigned short* __restrict__ xb, const unsigned short* __restrict__ wb,
    const float* __restrict__ bin)
{
    __shared__ union {
        struct {
            unsigned short piB[2][8192];      // 32 KB PI slabs (dbuf, padded)
            unsigned char  relS[T_STEPS * BATCH]; // 8 KB
            unsigned long long pref[T_STEPS];     // 2 KB
            float cS[NREL * 16];                  // 3.25 KB
            float red[2][2][5][256];              // 40 KB  (total 85.25 KB)
        } r;
        struct {
            unsigned short sA[128 * 32];      // 8 KB
            unsigned short sB[128 * 32];      // 8 KB
        } g;
    } sm;

    const int tid = threadIdx.x;
    const int w = tid >> 6, l = tid & 63;
    int* done = ctr + 1024;

    if (blockIdx.x >= 32) {
        // ================= GEMM role =================
        const int gbid = blockIdx.x - 32;
        const int wr = w >> 1, wc = w & 1;
        const int frow = l & 15, kg = (l >> 4) * 8;
        const int c0i = w * 128 + l;
        const int r0 = c0i >> 2, kc0 = (c0i & 3) * 8;
        const int c1i = c0i + 64;
        const int r1 = c1i >> 2, kc1 = (c1i & 3) * 8;
        unsigned short* lds0A = sm.g.sA + (w * 128) * 8;
        unsigned short* lds1A = sm.g.sA + (w * 128 + 64) * 8;
        unsigned short* lds0B = sm.g.sB + (w * 128) * 8;
        unsigned short* lds1B = sm.g.sB + (w * 128 + 64) * 8;

        for (int i = gbid; i < NTILES; i += GWGS) {
            const int by = i / 24, bx = i % 24;
            const long brow = (long)by * 128;
            const long bcol = (long)bx * 128;

            f32x4 acc[4][4] = {};
            for (int k0 = 0; k0 < DIN; k0 += 32) {
                __syncthreads();
                gll16(xb + (brow + r0) * DIN + k0 + kc0, lds0A);
                gll16(xb + (brow + r1) * DIN + k0 + kc1, lds1A);
                gll16(wb + (bcol + r0) * DIN + k0 + kc0, lds0B);
                gll16(wb + (bcol + r1) * DIN + k0 + kc1, lds1B);
                __syncthreads();
                bf16x8 aF[4], bF[4];
#pragma unroll
                for (int mm = 0; mm < 4; ++mm)
                    aF[mm] = *(const bf16x8*)(sm.g.sA + (wr * 64 + mm * 16 + frow) * 32 + kg);
#pragma unroll
                for (int nn = 0; nn < 4; ++nn)
                    bF[nn] = *(const bf16x8*)(sm.g.sB + (wc * 64 + nn * 16 + frow) * 32 + kg);
#pragma unroll
                for (int mm = 0; mm < 4; ++mm)
#pragma unroll
                    for (int nn = 0; nn < 4; ++nn)
                        acc[mm][nn] = __builtin_amdgcn_mfma_f32_16x16x32_bf16(aF[mm], bF[nn], acc[mm][nn], 0, 0, 0);
            }

            // epilogue: per-WG layout, coherent (sc0 sc1) stores -> L3
#pragma unroll
            for (int mm = 0; mm < 4; ++mm) {
#pragma unroll
                for (int nn = 0; nn < 4; ++nn) {
                    const long col = bcol + wc * 64 + nn * 16 + (l & 15);
                    const float bv = bin[col];
                    const int g2 = (int)(col >> 9);
                    const int cc = (int)(col & 511);
                    const size_t base = (size_t)(cc >> 4) * PIWG + (size_t)(g2 * 16 + (cc & 15));
#pragma unroll
                    for (int r = 0; r < 4; ++r) {
                        const long row = brow + wr * 64 + mm * 16 + (l >> 4) * 4 + r;
                        coh_store_u16(PI2 + base + (size_t)row * 96,
                                      (unsigned int)f2bf(acc[mm][nn][r] + bv));
                    }
                }
            }
            asm volatile("s_waitcnt vmcnt(0)" ::: "memory");
            __syncthreads();
            if (tid == 0) atomicAdd(&done[by], 1);
        }
        return;
    }

    // ================= RECURRENCE role (R11 body + done gating) =================
    const int slot = blockIdx.x;
    const int hc0 = slot * 16;
    const unsigned short* slabBase = PI2 + (size_t)slot * PIWG;
    unsigned short* HpL = Hp + 2 * SREL;
    int* myflag = ctr + slot * 32;

    unsigned char* relS = sm.r.relS;
    unsigned long long* pref = sm.r.pref;
    float* cS = sm.r.cS;

    for (int i = tid; i < T_STEPS * BATCH; i += 256) relS[i] = (unsigned char)rel[i];
    __syncthreads();

    {
        unsigned long long f = 0;
        for (int b = 0; b < BATCH; ++b) f ^= 1ull << relS[tid * BATCH + b];
        pref[tid] = f;
    }
    __syncthreads();
    if (tid == 0) {
        unsigned long long run = 0;
        for (int t = 0; t < T_STEPS; ++t) {
            const unsigned long long f = pref[t];
            pref[t] = run;
            run ^= f;
        }
    }

    const int m = w & 1, kh = w >> 1;
    const int frow = l & 15, koff = l >> 4;
    const int col = hc0 + frow;

    bf16x8 Wr[5][8];
#pragma unroll
    for (int g = 0; g < 5; ++g)
#pragma unroll
        for (int kk = 0; kk < 8; ++kk)
            Wr[g][kk] = *(const bf16x8*)(wsb + (size_t)(g * HD + hc0 + frow) * HD
                                         + kh * 256 + kk * 32 + koff * 8);

    for (int i = tid; i < NREL * 16; i += 256) {
        const int r = i >> 4, c = hc0 + (i & 15);
        cS[i] = c0[r * HD + c];
        const float hv = h0[r * HD + c];
        const unsigned short hi = f2bf(hv);
        coh_store_u16(Hp + r * HD + c, hi);
        coh_store_u16(HpL + r * HD + c, (unsigned int)f2bf(hv - bf2f(hi)));
    }

    // gate on row-block 0, then preload PI slab 0
    int readyUpto;
    {
        int dv, it = 0;
        do { dv = coh_load_i32(done + 0); } while (dv < 24 && ++it < SPIN_MAX);
        readyUpto = 1;
    }
    gll16(slabBase + (w * 64 + l) * 8, &sm.r.piB[0][0] + (w * 64 + l) * 8);
    gll16(slabBase + (256 + w * 64 + l) * 8, &sm.r.piB[0][0] + (256 + w * 64 + l) * 8);

    float bs0 = bst[col], bs1 = bst[HD + col], bs2 = bst[2 * HD + col];
    float bs3 = bst[3 * HD + col], bs4 = bst[4 * HD + col];
    const int rA = kh * 2, rB = rA + 1;
    const int bA = m * 16 + (l >> 4) * 4 + rA;
    const int bB = bA + 1;
    const float dropA = drop[bA * HD + col];
    const float dropB = drop[bB * HD + col];

    __syncthreads();
    asm volatile("s_waitcnt vmcnt(0)" ::: "memory");
    __builtin_amdgcn_s_barrier();
    if (tid == 64) coh_store_u32(myflag, 1);
    if (w == 0) {
        const int* fp = ctr + ((l < 32) ? l : 31) * 32;
        int fv, it = 0;
        do { fv = coh_load_i32(fp); } while (!__all(fv >= 1) && ++it < SPIN_MAX);
    }
    __syncthreads();

    for (int t = 0; t < T_STEPS; ++t) {
        const unsigned long long pm = pref[t];

        const int id = relS[t * BATCH + m * 16 + frow];
        const unsigned short* hp = Hp + (int)((pm >> id) & 1) * SREL + id * HD + kh * 256 + koff * 8;
        const unsigned short* lp = hp + 2 * SREL;
        V16 hF[8], lF[8];
        GATHER_PLANES(hF, lF, hp, lp);
        asm volatile("s_waitcnt vmcnt(8)" ::: "memory");
        __builtin_amdgcn_sched_barrier(0);

        f32x4 acch[5] = {}, accl[5] = {};
#pragma unroll
        for (int kk = 0; kk < 8; ++kk)
#pragma unroll
            for (int g = 0; g < 5; ++g)
                acch[g] = __builtin_amdgcn_mfma_f32_16x16x32_bf16(hF[kk].v, Wr[g][kk], acch[g], 0, 0, 0);

        asm volatile("s_waitcnt vmcnt(0)" ::: "memory");
        __builtin_amdgcn_sched_barrier(0);

#pragma unroll
        for (int kk = 0; kk < 8; ++kk)
#pragma unroll
            for (int g = 0; g < 5; ++g)
                accl[g] = __builtin_amdgcn_mfma_f32_16x16x32_bf16(lF[kk].v, Wr[g][kk], accl[g], 0, 0, 0);

        f32x4 own[5];
#pragma unroll
        for (int g = 0; g < 5; ++g) {
            own[g] = acch[g] + accl[g];
            *(f32x4*)&sm.r.red[m][kh][g][l * 4] = own[g];
        }
        __syncthreads();

        float hOutA, hOutB;
        int bAr, bBr;
        {
            float psA[5], psB[5];
#pragma unroll
            for (int g = 0; g < 5; ++g) {
                const f32x4 oth = *(const f32x4*)&sm.r.red[m][kh ^ 1][g][l * 4];
                psA[g] = own[g][rA] + oth[rA];
                psB[g] = own[g][rB] + oth[rB];
            }
            const unsigned short* pb = &sm.r.piB[t & 1][0];
            const unsigned short* prA = pb + bA * 96 + frow;
            const unsigned short* prB = pb + bB * 96 + frow;
            const int idA = relS[t * BATCH + bA];
            const int idB = relS[t * BATCH + bB];
            bAr = idA; bBr = idB;
            {
                const float ig = sigm(bf2f(prA[0])  + psA[0] + bs0);
                const float fg = sigm(bf2f(prA[16]) + psA[1] + bs1);
                const float gg = tanh_fast(bf2f(prA[32]) + psA[2] + bs2);
                const float og = sigm(bf2f(prA[48]) + psA[3] + bs3);
                const float hw = sigm(bf2f(prA[64]) + psA[4] + bs4);
                const float cp = cS[idA * 16 + frow];
                const float cn = ig * gg + fg * cp;
                float h = og * tanh_fast(cn);
                h = hw * h + (1.f - hw) * bf2f(prA[80]);
                h *= dropA;
                cS[idA * 16 + frow] = cn;
                hOutA = h;
            }
            {
                const float ig = sigm(bf2f(prB[0])  + psB[0] + bs0);
                const float fg = sigm(bf2f(prB[16]) + psB[1] + bs1);
                const float gg = tanh_fast(bf2f(prB[32]) + psB[2] + bs2);
                const float og = sigm(bf2f(prB[48]) + psB[3] + bs3);
                const float hw = sigm(bf2f(prB[64]) + psB[4] + bs4);
                const float cp = cS[idB * 16 + frow];
                const float cn = ig * gg + fg * cp;
                float h = og * tanh_fast(cn);
                h = hw * h + (1.f - hw) * bf2f(prB[80]);
                h *= dropB;
                cS[idB * 16 + frow] = cn;
                hOutB = h;
            }
        }

        // publishes(4) -> Hs(2) -> [done gate] -> PI prefetch(2)
        {
            const unsigned short hhiA = f2bf(hOutA);
            const unsigned short hloA = f2bf(hOutA - bf2f(hhiA));
            const unsigned short hhiB = f2bf(hOutB);
            const unsigned short hloB = f2bf(hOutB - bf2f(hhiB));
            const int pwA = (int)(((pm >> bAr) & 1) ^ 1ull);
            const int pwB = (int)(((pm >> bBr) & 1) ^ 1ull);
            coh_store_u16(Hp + pwA * SREL + bAr * HD + col, hhiA);
            coh_store_u16(HpL + pwA * SREL + bAr * HD + col, hloA);
            coh_store_u16(Hp + pwB * SREL + bBr * HD + col, hhiB);
            coh_store_u16(HpL + pwB * SREL + bBr * HD + col, hloB);
            plain_store_f32(Hs + (size_t)(t * BATCH + bA) * HD + col, hOutA);
            plain_store_f32(Hs + (size_t)(t * BATCH + bB) * HD + col, hOutB);
            __builtin_amdgcn_sched_barrier(0);

            if (t + 1 < T_STEPS && readyUpto < 64) {
                const int rb = (t + 1) >> 2;
                if (rb >= readyUpto) {
                    int dv = coh_load_i32(done + 63);     // all-complete shortcut
                    if (dv >= 24) readyUpto = 64;
                    else {
                        int it = 0;
                        do { dv = coh_load_i32(done + rb); } while (dv < 24 && ++it < SPIN_MAX);
                        readyUpto = rb + 1;
                    }
                }
            }

            const int tn = (t + 1 < T_STEPS) ? (t + 1) : 0;
            const unsigned short* gsl = slabBase + (size_t)tn * 3072;
            unsigned short* dst = &sm.r.piB[tn & 1][0];
            gll16(gsl + (w * 64 + l) * 8, dst + (w * 64 + l) * 8);
            gll16(gsl + (256 + w * 64 + l) * 8, dst + (256 + w * 64 + l) * 8);
            __builtin_amdgcn_sched_barrier(0);
        }

        asm volatile("s_waitcnt vmcnt(4)" ::: "memory");
        __builtin_amdgcn_sched_barrier(0);
        __builtin_amdgcn_s_barrier();

        if (tid == 64) coh_store_u32(myflag, t + 2);
        if (w == 0) {
            const int* fp = ctr + ((l < 32) ? l : 31) * 32;
            int fv, it = 0;
            do { fv = coh_load_i32(fp); } while (!__all(fv >= t + 2) && ++it < SPIN_MAX);
        }
        __syncthreads();
    }
}

// ---------- phase 3: preds = Hs @ W_out^T + b_out (fp32) ----------
__global__ __launch_bounds__(256) void k_pred(const float* __restrict__ Hs,
                                              const float* __restrict__ Wout,
                                              const float* __restrict__ bout,
                                              float* __restrict__ out) {
    __shared__ float hT[16 * HD];
    const int tid = threadIdx.x;
    const long row0 = (long)blockIdx.x * 16;
    for (int i = tid; i < (16 * HD) / 4; i += 256)
        ((float4*)hT)[i] = ((const float4*)(Hs + row0 * HD))[i];
    __syncthreads();
    const int w = tid >> 6, c = tid & 63;
    if (c < NREL) {
        float a0 = bout[c], a1 = a0, a2 = a0, a3 = a0;
        const float* wrp = Wout + c * HD;
        for (int k = 0; k < HD; k += 4) {
            const float4 wv = *(const float4*)(wrp + k);
            const float4 h0 = *(const float4*)(hT + (w * 4 + 0) * HD + k);
            const float4 h1 = *(const float4*)(hT + (w * 4 + 1) * HD + k);
            const float4 h2 = *(const float4*)(hT + (w * 4 + 2) * HD + k);
            const float4 h3 = *(const float4*)(hT + (w * 4 + 3) * HD + k);
            a0 += wv.x * h0.x + wv.y * h0.y + wv.z * h0.z + wv.w * h0.w;
            a1 += wv.x * h1.x + wv.y * h1.y + wv.z * h1.z + wv.w * h1.w;
            a2 += wv.x * h2.x + wv.y * h2.y + wv.z * h2.z + wv.w * h2.w;
            a3 += wv.x * h3.x + wv.y * h3.y + wv.z * h3.z + wv.w * h3.w;
        }
        out[(row0 + w * 4 + 0) * NREL + c] = a0;
        out[(row0 + w * 4 + 1) * NREL + c] = a1;
        out[(row0 + w * 4 + 2) * NREL + c] = a2;
        out[(row0 + w * 4 + 3) * NREL + c] = a3;
    }
}

extern "C" void kernel_launch(void* const* d_in, const int* in_sizes, int n_in,
                              void* d_out, int out_size, void* d_ws, size_t ws_size,
                              hipStream_t stream) {
    const float* x    = (const float*)d_in[0];
    const int*   rel  = (const int*)  d_in[1];
    const float* h0   = (const float*)d_in[2];
    const float* c0   = (const float*)d_in[3];
    const float* Win  = (const float*)d_in[4];
    const float* bin  = (const float*)d_in[5];
    const float* Wst  = (const float*)d_in[6];
    const float* bst  = (const float*)d_in[7];
    const float* Wout = (const float*)d_in[8];
    const float* bout = (const float*)d_in[9];
    const float* drop = (const float*)d_in[10];

    char* ws = (char*)d_ws;
    // workspace layout (bytes), total ~162.3 MB
    unsigned short* xb  = (unsigned short*)(ws);              // 67,108,864
    unsigned short* wb  = (unsigned short*)(ws + 67108864);   // 25,165,824
    unsigned short* wsb = (unsigned short*)(ws + 92274688);   //  2,621,440
    unsigned short* PI2 = (unsigned short*)(ws + 94896128);   // 50,331,648
    unsigned short* Hp  = (unsigned short*)(ws + 145227776);  //    208,896 (hi/lo x 2 parity)
    float*          Hs  = (float*)         (ws + 145436672);  // 16,777,216
    int*            ctr = (int*)           (ws + 162213888);  //      8,192 (flags + done)
    float* out = (float*)d_out;

    k_zero<<<8, 256, 0, stream>>>(ctr);
    k_cvt<<<2048, 256, 0, stream>>>(x, xb, (TB * DIN) / 4);
    k_cvt<<<1024, 256, 0, stream>>>(Win, wb, (SIXH * DIN) / 4);
    k_cvt<<<320, 256, 0, stream>>>(Wst, wsb, (FIVEH * HD) / 4);

    k_main<<<256, 256, 0, stream>>>(rel, h0, c0, PI2, wsb, bst, drop, Hp, ctr, Hs,
                                    xb, wb, bin);

    k_pred<<<512, 256, 0, stream>>>(Hs, Wout, bout, out);
}